// Round 16
// baseline (121.643 us; speedup 1.0000x reference)
//
#include <hip/hip_runtime.h>
#include <math.h>

namespace {
constexpr int kN    = 8192;
constexpr int kC    = 256;
constexpr int kRowsTotal = 2 * kN;  // B*N = 16384
constexpr float kScale = 0.17677669529663687f;  // 32^-0.5
}

typedef __attribute__((ext_vector_type(8))) short bf16x8;
typedef __attribute__((ext_vector_type(4))) float f32x4;
typedef _Float16 h8 __attribute__((ext_vector_type(8)));
typedef _Float16 h4 __attribute__((ext_vector_type(4)));
typedef _Float16 h2 __attribute__((ext_vector_type(2)));

__device__ __forceinline__ unsigned short f2bf(float f) {
  unsigned int u = __float_as_uint(f);
  u += 0x7fffu + ((u >> 16) & 1u);   // round-to-nearest-even
  return (unsigned short)(u >> 16);
}
__device__ __forceinline__ unsigned short f2h(float f) {
  _Float16 h = (_Float16)f;
  unsigned short u;
  __builtin_memcpy(&u, &h, 2);
  return u;
}
__device__ __forceinline__ float h2f(unsigned short u) {
  _Float16 h;
  __builtin_memcpy(&h, &u, 2);
  return (float)h;
}

#if __has_builtin(__builtin_amdgcn_fdot2)
__device__ __forceinline__ float fdot2f(h2 a, h2 b, float c) {
  return __builtin_amdgcn_fdot2(a, b, c, false);
}
#else
__device__ __forceinline__ float fdot2f(h2 a, h2 b, float c) {
  return fmaf((float)a[0], (float)b[0], fmaf((float)a[1], (float)b[1], c));
}
#endif

#define GLOAD16(g, l)                                                   \
  __builtin_amdgcn_global_load_lds(                                     \
      (const __attribute__((address_space(1))) void*)(g),               \
      (__attribute__((address_space(3))) void*)(l), 16, 0, 0)

// ---- prep: weights cast (bid<2052) | posm (else) ---------------------------
__global__ __launch_bounds__(256) void prep_kernel(
    const float* __restrict__ qw, const float* __restrict__ kvw,
    const float* __restrict__ pjw, const float* __restrict__ f1w,
    const float* __restrict__ f2w, const float* __restrict__ qb,
    const float* __restrict__ kvb, const float* __restrict__ bk,
    const int* __restrict__ pe_idx, const float* __restrict__ pre_table,
    const float* __restrict__ pe_w, const float* __restrict__ pe_b,
    const float* __restrict__ cmask, unsigned short* __restrict__ wqkv,
    unsigned short* __restrict__ wproj, unsigned short* __restrict__ wfc1,
    unsigned short* __restrict__ wfc2, float* __restrict__ bqkv,
    unsigned short* __restrict__ bkh, unsigned short* __restrict__ posm) {
  int bid = blockIdx.x;
  int t = threadIdx.x;
  if (bid < 2052) {
    int i = bid * 256 + t;
    if (i < 65536)       wqkv[i]            = f2bf(qw[i]);
    else if (i < 196608) wqkv[i]            = f2bf(kvw[i - 65536]);
    else if (i < 262144) wproj[i - 196608]  = f2bf(pjw[i - 196608]);
    else if (i < 393216) wfc1[i - 262144]   = f2bf(f1w[i - 262144]);
    else if (i < 524288) wfc2[i - 393216]   = f2bf(f2w[i - 393216]);
    else if (i < 524544) bqkv[i - 524288]   = qb[i - 524288];
    else if (i < 525056) bqkv[i - 524288]   = kvb[i - 524544];
    else if (i < 525312) bkh[i - 525056]    = f2h(bk[i - 525056]);
  } else {
    int i = (bid - 2052) * 256 + t;
    int row = i >> 8, m = (i >> 3) & 31, h = i & 7;
    int idx = pe_idx[(size_t)row * 32 + m];
    float acc = pe_b[h];
#pragma unroll
    for (int f = 0; f < 5; ++f)
      acc += pre_table[idx * 5 + f] * pe_w[h * 5 + f];
    acc += (1.0f - cmask[(size_t)row * 32 + m]) * -100.0f;
    posm[(size_t)row * 256 + h * 32 + m] = f2h(acc);
  }
}

// ---- fused LN1 + QKV GEMM: BM=32, A K-chunked [8][32][32], 3 blocks/CU -----
__global__ __launch_bounds__(512) void qkv_fused(
    const float* __restrict__ feat, const float* __restrict__ n1w,
    const float* __restrict__ n1b, const unsigned short* __restrict__ Wq,
    const float* __restrict__ bqkv, unsigned short* __restrict__ qo,
    unsigned short* __restrict__ ko, unsigned short* __restrict__ vo) {
  __shared__ alignas(16) unsigned short sm[24576]; // A 8192 | Bs dbuf 2x8192
  int t = threadIdx.x;
  int w = t >> 6, l = t & 63;
  int bm = blockIdx.x * 32;
  const int lr = l & 15, lk = l >> 4;

  // ---- LN1 -> A chunks (16 threads/row) ----
  {
    int r = t >> 4, sub = t & 15;
    float4 xv[4];
    float sx = 0.f, sxx = 0.f;
#pragma unroll
    for (int i = 0; i < 4; ++i) {
      xv[i] = *(const float4*)(feat + (size_t)(bm + r) * 256 + sub * 4 + i * 64);
      sx  += xv[i].x + xv[i].y + xv[i].z + xv[i].w;
      sxx += xv[i].x * xv[i].x + xv[i].y * xv[i].y + xv[i].z * xv[i].z +
             xv[i].w * xv[i].w;
    }
#pragma unroll
    for (int d = 1; d < 16; d <<= 1) {
      sx  += __shfl_xor(sx, d, 64);
      sxx += __shfl_xor(sxx, d, 64);
    }
    float mu = sx * (1.0f / 256.0f);
    float rstd = rsqrtf(sxx * (1.0f / 256.0f) - mu * mu + 1e-5f);
#pragma unroll
    for (int i = 0; i < 4; ++i) {
      int c = sub * 4 + i * 64;
      float4 wv = *(const float4*)(n1w + c);
      float4 bv = *(const float4*)(n1b + c);
      uint2 ov;
      ov.x = ((unsigned int)f2bf((xv[i].y - mu) * rstd * wv.y + bv.y) << 16) |
             f2bf((xv[i].x - mu) * rstd * wv.x + bv.x);
      ov.y = ((unsigned int)f2bf((xv[i].w - mu) * rstd * wv.w + bv.w) << 16) |
             f2bf((xv[i].z - mu) * rstd * wv.z + bv.z);
      *(uint2*)&sm[(c >> 5) * 1024 + r * 32 + (c & 31)] = ov;
    }
  }

#define QSTAGE(buf, k0, bn)                                                   \
  do {                                                                        \
    GLOAD16(Wq + (size_t)((bn)*256 + w * 32 + (l >> 2)) * 256 + (k0) +        \
                (l & 3) * 8,                                                  \
            sm + 8192 + (buf)*8192 + w * 1024 + l * 8);                       \
    GLOAD16(Wq + (size_t)((bn)*256 + w * 32 + 16 + (l >> 2)) * 256 + (k0) +   \
                (l & 3) * 8,                                                  \
            sm + 8192 + (buf)*8192 + w * 1024 + 512 + l * 8);                 \
  } while (0)

#pragma unroll
  for (int bn = 0; bn < 3; ++bn) {
    f32x4 acc[2][2] = {};
    auto computeQ = [&](int buf, int ka) {
      bf16x8 af[2], bfr[2];
#pragma unroll
      for (int mi = 0; mi < 2; ++mi)
        af[mi] = *(const bf16x8*)(sm + (ka >> 5) * 1024 + (mi * 16 + lr) * 32 +
                                  lk * 8);
#pragma unroll
      for (int ni = 0; ni < 2; ++ni)
        bfr[ni] = *(const bf16x8*)(sm + 8192 + buf * 8192 +
                                   (w * 32 + ni * 16 + lr) * 32 + lk * 8);
#pragma unroll
      for (int mi = 0; mi < 2; ++mi)
#pragma unroll
        for (int ni = 0; ni < 2; ++ni)
          acc[mi][ni] = __builtin_amdgcn_mfma_f32_16x16x32_bf16(
              af[mi], bfr[ni], acc[mi][ni], 0, 0, 0);
    };
    QSTAGE(0, 0, bn);
    __syncthreads();
    int cur = 0;
#pragma unroll
    for (int k0 = 32; k0 < 256; k0 += 32) {
      QSTAGE(cur ^ 1, k0, bn);
      computeQ(cur, k0 - 32);
      __syncthreads();
      cur ^= 1;
    }
    computeQ(cur, 224);

#pragma unroll
    for (int mi = 0; mi < 2; ++mi) {
#pragma unroll
      for (int ni = 0; ni < 2; ++ni) {
        int col = bn * 256 + w * 32 + ni * 16 + lr;
        float bv = bqkv[col];
#pragma unroll
        for (int j = 0; j < 4; ++j) {
          int rg = bm + mi * 16 + lk * 4 + j;
          float x = acc[mi][ni][j] + bv;
          if (col < 256) {
            qo[(size_t)rg * 256 + col] = f2h(x * kScale);
          } else {
            int c = col - 256;
            int h = c >> 6, sbit = (c >> 5) & 1, ch = c & 31;
            unsigned short* dst = sbit ? vo : ko;
            dst[(size_t)rg * 256 + h * 32 + ch] = f2h(x);
          }
        }
      }
    }
    __syncthreads();
  }
#undef QSTAGE
}

// ---- proj + residual + LN2: BM=32, A chunked staged once, 3 blocks/CU ------
__global__ __launch_bounds__(512) void proj_ln2(
    const unsigned short* __restrict__ A, const unsigned short* __restrict__ Wp,
    const float* __restrict__ pbias, const float* __restrict__ feat,
    const float* __restrict__ w2, const float* __restrict__ b2,
    float* __restrict__ x_out, unsigned short* __restrict__ yln) {
  __shared__ alignas(16) unsigned short sm[24576]; // A 8192 | Bs dbuf 2x8192
  int t = threadIdx.x;
  int w = t >> 6, l = t & 63;
  int bm = blockIdx.x * 32;
  const int lr = l & 15, lk = l >> 4;

  // ---- stage A (attn_out rows) as K-chunks [8][32][32]: 2 GLOADs ----
#pragma unroll
  for (int g = 0; g < 2; ++g) {
    int chunk = g * 4 + (t >> 7);
    int row = (t >> 2) & 31;
    GLOAD16(A + (size_t)(bm + row) * 256 + chunk * 32 + (t & 3) * 8,
            sm + g * 4096 + w * 512 + l * 8);
  }

#define PSTAGE(buf, k0)                                                       \
  do {                                                                        \
    GLOAD16(Wp + (size_t)(w * 32 + (l >> 2)) * 256 + (k0) + (l & 3) * 8,      \
            sm + 8192 + (buf)*8192 + w * 1024 + l * 8);                       \
    GLOAD16(Wp + (size_t)(w * 32 + 16 + (l >> 2)) * 256 + (k0) + (l & 3) * 8, \
            sm + 8192 + (buf)*8192 + w * 1024 + 512 + l * 8);                 \
  } while (0)

  f32x4 acc[2][2] = {};
  auto computeP = [&](int buf, int ka) {
    bf16x8 af[2], bfr[2];
#pragma unroll
    for (int mi = 0; mi < 2; ++mi)
      af[mi] = *(const bf16x8*)(sm + (ka >> 5) * 1024 + (mi * 16 + lr) * 32 +
                                lk * 8);
#pragma unroll
    for (int ni = 0; ni < 2; ++ni)
      bfr[ni] = *(const bf16x8*)(sm + 8192 + buf * 8192 +
                                 (w * 32 + ni * 16 + lr) * 32 + lk * 8);
#pragma unroll
    for (int mi = 0; mi < 2; ++mi)
#pragma unroll
      for (int ni = 0; ni < 2; ++ni)
        acc[mi][ni] = __builtin_amdgcn_mfma_f32_16x16x32_bf16(
            af[mi], bfr[ni], acc[mi][ni], 0, 0, 0);
  };
  PSTAGE(0, 0);
  __syncthreads();
  int cur = 0;
#pragma unroll
  for (int k0 = 32; k0 < 256; k0 += 32) {
    PSTAGE(cur ^ 1, k0);
    computeP(cur, k0 - 32);
    __syncthreads();
    cur ^= 1;
  }
  computeP(cur, 224);
#undef PSTAGE

  // ---- x = acc + bias + feat -> xs (LDS f32) + x_out global ----
  __syncthreads();
  float* xs = (float*)sm;   // [32][260]
#pragma unroll
  for (int mi = 0; mi < 2; ++mi) {
#pragma unroll
    for (int ni = 0; ni < 2; ++ni) {
      int c = w * 32 + ni * 16 + lr;
      float bv = pbias[c];
#pragma unroll
      for (int j = 0; j < 4; ++j) {
        int rl = mi * 16 + lk * 4 + j;
        float x = acc[mi][ni][j] + bv + feat[(size_t)(bm + rl) * 256 + c];
        xs[rl * 260 + c] = x;
        x_out[(size_t)(bm + rl) * 256 + c] = x;
      }
    }
  }
  __syncthreads();

  // ---- LN2 -> yln global (16 threads/row) ----
  {
    int r = t >> 4, sub = t & 15;
    float4 xv[4];
    float sx = 0.f, sxx = 0.f;
#pragma unroll
    for (int i = 0; i < 4; ++i) {
      xv[i] = *(const float4*)&xs[r * 260 + sub * 4 + i * 64];
      sx  += xv[i].x + xv[i].y + xv[i].z + xv[i].w;
      sxx += xv[i].x * xv[i].x + xv[i].y * xv[i].y + xv[i].z * xv[i].z +
             xv[i].w * xv[i].w;
    }
#pragma unroll
    for (int d = 1; d < 16; d <<= 1) {
      sx  += __shfl_xor(sx, d, 64);
      sxx += __shfl_xor(sxx, d, 64);
    }
    float mu = sx * (1.0f / 256.0f);
    float rstd = rsqrtf(sxx * (1.0f / 256.0f) - mu * mu + 1e-5f);
#pragma unroll
    for (int i = 0; i < 4; ++i) {
      int c = sub * 4 + i * 64;
      float4 wv = *(const float4*)(w2 + c);
      float4 bv = *(const float4*)(b2 + c);
      uint2 ov;
      ov.x = ((unsigned int)f2bf((xv[i].y - mu) * rstd * wv.y + bv.y) << 16) |
             f2bf((xv[i].x - mu) * rstd * wv.x + bv.x);
      ov.y = ((unsigned int)f2bf((xv[i].w - mu) * rstd * wv.w + bv.w) << 16) |
             f2bf((xv[i].z - mu) * rstd * wv.z + bv.z);
      *(uint2*)(yln + (size_t)(bm + r) * 256 + c) = ov;
    }
  }
}

// ---- fc1 + gelu + fc2 + residual: BM=32, h1 K-chunked in LDS, 2 blocks/CU --
// LDS shorts [40960]=81920B: h1 [16][32][32] @0 | W dbuf 2x8192 @16384 |
//                            A(yln) [8][32][32] @32768
__global__ __launch_bounds__(512) void fc_fused(
    const unsigned short* __restrict__ yln, const unsigned short* __restrict__ W1,
    const float* __restrict__ b1, const unsigned short* __restrict__ W2,
    const float* __restrict__ b2f, float* __restrict__ xio) {
  __shared__ alignas(16) unsigned short sm[40960];
  int t = threadIdx.x;
  int w = t >> 6, l = t & 63;
  int bm = blockIdx.x * 32;
  const int lr = l & 15, lk = l >> 4;

  // ---- stage A (yln rows) as K-chunks [8][32][32] @32768 ----
#pragma unroll
  for (int g = 0; g < 2; ++g) {
    int chunk = g * 4 + (t >> 7);
    int row = (t >> 2) & 31;
    GLOAD16(yln + (size_t)(bm + row) * 256 + chunk * 32 + (t & 3) * 8,
            sm + 32768 + g * 4096 + w * 512 + l * 8);
  }

#define WSTAGE(buf, src, ldw, rowoff, k0)                                     \
  do {                                                                        \
    GLOAD16((src) + (size_t)((rowoff) + w * 32 + (l >> 2)) * (ldw) + (k0) +   \
                (l & 3) * 8,                                                  \
            sm + 16384 + (buf)*8192 + w * 1024 + l * 8);                      \
    GLOAD16((src) + (size_t)((rowoff) + w * 32 + 16 + (l >> 2)) * (ldw) +     \
                (k0) + (l & 3) * 8,                                           \
            sm + 16384 + (buf)*8192 + w * 1024 + 512 + l * 8);                \
  } while (0)

  // ---------------- fc1 + gelu -> h1 chunks @0 ----------------
#pragma unroll
  for (int c = 0; c < 2; ++c) {
    f32x4 accf[2][2] = {};
    auto computeF1 = [&](int buf, int ka) {
      bf16x8 af[2], bfr[2];
#pragma unroll
      for (int mi = 0; mi < 2; ++mi)
        af[mi] = *(const bf16x8*)(sm + 32768 + (ka >> 5) * 1024 +
                                  (mi * 16 + lr) * 32 + lk * 8);
#pragma unroll
      for (int ni = 0; ni < 2; ++ni)
        bfr[ni] = *(const bf16x8*)(sm + 16384 + buf * 8192 +
                                   (w * 32 + ni * 16 + lr) * 32 + lk * 8);
#pragma unroll
      for (int mi = 0; mi < 2; ++mi)
#pragma unroll
        for (int ni = 0; ni < 2; ++ni)
          accf[mi][ni] = __builtin_amdgcn_mfma_f32_16x16x32_bf16(
              af[mi], bfr[ni], accf[mi][ni], 0, 0, 0);
    };
    WSTAGE(0, W1, 256, c * 256, 0);
    __syncthreads();
    int cur = 0;
#pragma unroll
    for (int k0 = 32; k0 < 256; k0 += 32) {
      WSTAGE(cur ^ 1, W1, 256, c * 256, k0);
      computeF1(cur, k0 - 32);
      __syncthreads();
      cur ^= 1;
    }
    computeF1(cur, 224);
    // gelu -> h1 chunk (chunk index = c*8 + w)
#pragma unroll
    for (int mi = 0; mi < 2; ++mi) {
#pragma unroll
      for (int ni = 0; ni < 2; ++ni) {
        int cl = w * 32 + ni * 16 + lr;       // col within 256-chunk
        float bv = b1[c * 256 + cl];
#pragma unroll
        for (int j = 0; j < 4; ++j) {
          int row = mi * 16 + lk * 4 + j;
          float x = accf[mi][ni][j] + bv;
          float g = 0.5f * x * (1.0f + erff(x * 0.70710678118654752f));
          int colg = c * 256 + cl;
          sm[(colg >> 5) * 1024 + row * 32 + (colg & 31)] = f2bf(g);
        }
      }
    }
    __syncthreads();
  }

  // ---------------- fc2 (K=512, BK=32) + residual -> out ----------------
  f32x4 acc2[2][2] = {};
  auto computeF2 = [&](int buf, int ka) {
    bf16x8 af[2], bfr[2];
#pragma unroll
    for (int mi = 0; mi < 2; ++mi)
      af[mi] = *(const bf16x8*)(sm + (ka >> 5) * 1024 + (mi * 16 + lr) * 32 +
                                lk * 8);
#pragma unroll
    for (int ni = 0; ni < 2; ++ni)
      bfr[ni] = *(const bf16x8*)(sm + 16384 + buf * 8192 +
                                 (w * 32 + ni * 16 + lr) * 32 + lk * 8);
#pragma unroll
    for (int mi = 0; mi < 2; ++mi)
#pragma unroll
      for (int ni = 0; ni < 2; ++ni)
        acc2[mi][ni] = __builtin_amdgcn_mfma_f32_16x16x32_bf16(
            af[mi], bfr[ni], acc2[mi][ni], 0, 0, 0);
  };
  WSTAGE(0, W2, 512, 0, 0);
  __syncthreads();
  int cur = 0;
#pragma unroll
  for (int k0 = 32; k0 < 512; k0 += 32) {
    WSTAGE(cur ^ 1, W2, 512, 0, k0);
    computeF2(cur, k0 - 32);
    __syncthreads();
    cur ^= 1;
  }
  computeF2(cur, 480);
#undef WSTAGE

#pragma unroll
  for (int mi = 0; mi < 2; ++mi) {
#pragma unroll
    for (int ni = 0; ni < 2; ++ni) {
      int col = w * 32 + ni * 16 + lr;
      float bv = b2f[col];
#pragma unroll
      for (int j = 0; j < 4; ++j) {
        int rg = bm + mi * 16 + lk * 4 + j;
        xio[(size_t)rg * 256 + col] =
            xio[(size_t)rg * 256 + col] + acc2[mi][ni][j] + bv;
      }
    }
  }
}

// -------- Attention (r15, unchanged): XCD-partitioned, f16, dot2 ------------
__global__ __launch_bounds__(256) void attn_kernel(
    const unsigned short* __restrict__ q, const unsigned short* __restrict__ k,
    const unsigned short* __restrict__ v, const int* __restrict__ member_idx,
    const unsigned short* __restrict__ posm,
    const unsigned short* __restrict__ bkh, const float* __restrict__ blank_v,
    unsigned short* __restrict__ outp) {
  int t = threadIdx.x;
  int w = t >> 6, l = t & 63;
  int bid = blockIdx.x;
  int part = bid & 7;
  int bb = part >> 2, hg = part & 3;
  int row = bb * kN + (bid >> 3) * 4 + w;
  const unsigned int kvbyte = (unsigned int)bb * (kN * 512u);

  __shared__ float        aw[4][2][36];
  __shared__ unsigned int offs[4][32];
  __shared__ float        posl[4][2][32];

  {
    int m = l & 31, hloc = l >> 5;
    posl[w][hloc][m] = h2f(posm[(size_t)row * 256 + hg * 64 + l]);
    if (l < 32)
      offs[w][l] =
          kvbyte + (unsigned int)member_idx[(size_t)row * 32 + l] * 512u;
  }
  __syncthreads();

  const int m8 = l >> 3, ch = l & 7;
  const int hsel = ch >> 2;

  h8 qv8 = *(const h8*)(q + (size_t)row * 256 + hg * 64 + ch * 8);
  const h2* qa = (const h2*)&qv8;

  float lg[4];
#pragma unroll
  for (int i = 0; i < 4; ++i) {
    int mi = i * 8 + m8;
    const char* kp = (const char*)k + offs[w][mi] + hg * 128 + ch * 16;
    h8 kv = *(const h8*)kp;
    const h2* ka = (const h2*)&kv;
    float p = 0.f;
#pragma unroll
    for (int e = 0; e < 4; ++e) p = fdot2f(qa[e], ka[e], p);
    p += __shfl_xor(p, 1, 64);
    p += __shfl_xor(p, 2, 64);
    lg[i] = p + posl[w][hsel][mi];
  }

  float bl = 0.f;
  {
    h8 bk8 = *(const h8*)(bkh + hg * 64 + ch * 8);
    const h2* ba = (const h2*)&bk8;
#pragma unroll
    for (int e = 0; e < 4; ++e) bl = fdot2f(qa[e], ba[e], bl);
    bl += __shfl_xor(bl, 1, 64);
    bl += __shfl_xor(bl, 2, 64);
    bl = fminf(fmaxf(bl, -5.0f), 5.0f);
  }

  float mx = fmaxf(fmaxf(lg[0], lg[1]), fmaxf(lg[2], lg[3]));
  mx = fmaxf(mx, __shfl_xor(mx, 8, 64));
  mx = fmaxf(mx, __shfl_xor(mx, 16, 64));
  mx = fmaxf(mx, __shfl_xor(mx, 32, 64));
  mx = fmaxf(mx, bl);
  float e4[4], s = 0.f;
#pragma unroll
  for (int i = 0; i < 4; ++i) { e4[i] = __expf(lg[i] - mx); s += e4[i]; }
  s += __shfl_xor(s, 8, 64);
  s += __shfl_xor(s, 16, 64);
  s += __shfl_xor(s, 32, 64);
  float eb = __expf(bl - mx);
  s += eb;
  float inv = __builtin_amdgcn_rcpf(s);
  if ((ch & 3) == 0) {
#pragma unroll
    for (int i = 0; i < 4; ++i) aw[w][hsel][i * 8 + m8] = e4[i] * inv;
    if (m8 == 0) aw[w][hsel][32] = eb * inv;
  }
  __syncthreads();

  const int hp = l >> 5, sq = (l >> 3) & 3, c8 = l & 7;
  const char* vb = (const char*)v + (hg * 2 + hp) * 64 + c8 * 8;
  float a0 = 0.f, a1 = 0.f, a2 = 0.f, a3 = 0.f;
#pragma unroll
  for (int i = 0; i < 8; ++i) {
    int mm = sq * 8 + i;
    float a = aw[w][hp][mm];
    h4 u = *(const h4*)(vb + offs[w][mm]);
    a0 = fmaf(a, (float)u[0], a0);
    a1 = fmaf(a, (float)u[1], a1);
    a2 = fmaf(a, (float)u[2], a2);
    a3 = fmaf(a, (float)u[3], a3);
  }
  a0 += __shfl_xor(a0, 8, 64);  a1 += __shfl_xor(a1, 8, 64);
  a2 += __shfl_xor(a2, 8, 64);  a3 += __shfl_xor(a3, 8, 64);
  a0 += __shfl_xor(a0, 16, 64); a1 += __shfl_xor(a1, 16, 64);
  a2 += __shfl_xor(a2, 16, 64); a3 += __shfl_xor(a3, 16, 64);
  if (sq == 0) {
    float ab = aw[w][hp][32];
    int c = (hg * 2 + hp) * 32 + c8 * 4;
    float4 bv = *(const float4*)(blank_v + c);
    a0 = fmaf(ab, bv.x, a0);
    a1 = fmaf(ab, bv.y, a1);
    a2 = fmaf(ab, bv.z, a2);
    a3 = fmaf(ab, bv.w, a3);
    uint2 o;
    o.x = ((unsigned int)f2bf(a1) << 16) | f2bf(a0);
    o.y = ((unsigned int)f2bf(a3) << 16) | f2bf(a2);
    *(uint2*)(outp + (size_t)row * 256 + c) = o;
  }
}

extern "C" void kernel_launch(void* const* d_in, const int* in_sizes, int n_in,
                              void* d_out, int out_size, void* d_ws, size_t ws_size,
                              hipStream_t stream) {
  const float* feat       = (const float*)d_in[0];
  const int*   member_idx = (const int*)d_in[1];
  const float* cmask      = (const float*)d_in[2];
  const int*   pe_idx     = (const int*)d_in[3];
  const float* pre_table  = (const float*)d_in[5];
  const float* n1w        = (const float*)d_in[6];
  const float* n1b        = (const float*)d_in[7];
  const float* q_w        = (const float*)d_in[8];
  const float* q_b        = (const float*)d_in[9];
  const float* kv_w       = (const float*)d_in[10];
  const float* kv_b       = (const float*)d_in[11];
  const float* blank_k    = (const float*)d_in[12];
  const float* blank_v    = (const float*)d_in[13];
  const float* pe_w       = (const float*)d_in[14];
  const float* pe_b       = (const float*)d_in[15];
  const float* proj_w     = (const float*)d_in[16];
  const float* proj_b     = (const float*)d_in[17];
  const float* n2w        = (const float*)d_in[18];
  const float* n2b        = (const float*)d_in[19];
  const float* fc1_w      = (const float*)d_in[20];
  const float* fc1_b      = (const float*)d_in[21];
  const float* fc2_w      = (const float*)d_in[22];
  const float* fc2_b      = (const float*)d_in[23];

  float* out = (float*)d_out;
  unsigned char* ws = (unsigned char*)d_ws;

  unsigned short* attn_out = (unsigned short*)(ws + 0);        // 8 MB
  unsigned short* q_buf = (unsigned short*)(ws + 8388608);     // 8 MB f16, later yln
  unsigned short* k_buf = (unsigned short*)(ws + 16777216);    // 8 MB f16
  unsigned short* v_buf = (unsigned short*)(ws + 25165824);    // 8 MB f16
  unsigned short* wqkv  = (unsigned short*)(ws + 33554432);    // 384 KB
  unsigned short* wproj = (unsigned short*)(ws + 33947648);    // 128 KB
  unsigned short* wfc1  = (unsigned short*)(ws + 34078720);    // 256 KB
  unsigned short* wfc2  = (unsigned short*)(ws + 34340864);    // 256 KB
  float*          bqkv  = (float*)(ws + 34603008);             // 3 KB
  unsigned short* bkh   = (unsigned short*)(ws + 34606080);    // 512 B
  unsigned short* posm  = (unsigned short*)out;  // d_out dead until proj_ln2
  unsigned short* yln   = q_buf;                 // q dead after attn

  prep_kernel<<<18436, 256, 0, stream>>>(
      q_w, kv_w, proj_w, fc1_w, fc2_w, q_b, kv_b, blank_k, pe_idx, pre_table,
      pe_w, pe_b, cmask, wqkv, wproj, wfc1, wfc2, bqkv, bkh, posm);

  qkv_fused<<<kRowsTotal / 32, 512, 0, stream>>>(
      feat, n1w, n1b, wqkv, bqkv, q_buf, k_buf, v_buf);

  attn_kernel<<<kRowsTotal, 256, 0, stream>>>(
      q_buf, k_buf, v_buf, member_idx, posm, bkh, blank_v, attn_out);

  proj_ln2<<<kRowsTotal / 32, 512, 0, stream>>>(
      attn_out, wproj, proj_b, feat, n2w, n2b, out, yln);

  fc_fused<<<kRowsTotal / 32, 512, 0, stream>>>(
      yln, wfc1, fc1_b, wfc2, fc2_b, out);
}

// Round 17
// 109.034 us; speedup vs baseline: 1.1156x; 1.1156x over previous
//
#include <hip/hip_runtime.h>
#include <math.h>

namespace {
constexpr int kN    = 8192;
constexpr int kC    = 256;
constexpr int kRowsTotal = 2 * kN;  // B*N = 16384
constexpr float kScale = 0.17677669529663687f;  // 32^-0.5
}

typedef __attribute__((ext_vector_type(8))) short bf16x8;
typedef __attribute__((ext_vector_type(4))) float f32x4;
typedef _Float16 h8 __attribute__((ext_vector_type(8)));
typedef _Float16 h4 __attribute__((ext_vector_type(4)));

__device__ __forceinline__ unsigned short f2bf(float f) {
  unsigned int u = __float_as_uint(f);
  u += 0x7fffu + ((u >> 16) & 1u);   // round-to-nearest-even
  return (unsigned short)(u >> 16);
}
__device__ __forceinline__ unsigned short f2h(float f) {
  _Float16 h = (_Float16)f;
  unsigned short u;
  __builtin_memcpy(&u, &h, 2);
  return u;
}
__device__ __forceinline__ float h2f(unsigned short u) {
  _Float16 h;
  __builtin_memcpy(&h, &u, 2);
  return (float)h;
}

#define GLOAD16(g, l)                                                   \
  __builtin_amdgcn_global_load_lds(                                     \
      (const __attribute__((address_space(1))) void*)(g),               \
      (__attribute__((address_space(3))) void*)(l), 16, 0, 0)

// ---- prep: weights cast (bid<2052) | LN1 (bid<6148) | posm (else) ----------
__global__ __launch_bounds__(256) void prep_kernel(
    const float* __restrict__ qw, const float* __restrict__ kvw,
    const float* __restrict__ pjw, const float* __restrict__ f1w,
    const float* __restrict__ f2w, const float* __restrict__ qb,
    const float* __restrict__ kvb, const float* __restrict__ bk,
    const float* __restrict__ feat, const float* __restrict__ n1w,
    const float* __restrict__ n1b, const int* __restrict__ pe_idx,
    const float* __restrict__ pre_table, const float* __restrict__ pe_w,
    const float* __restrict__ pe_b, const float* __restrict__ cmask,
    unsigned short* __restrict__ wqkv, unsigned short* __restrict__ wproj,
    unsigned short* __restrict__ wfc1, unsigned short* __restrict__ wfc2,
    float* __restrict__ bqkv, unsigned short* __restrict__ bkh,
    unsigned short* __restrict__ xln, unsigned short* __restrict__ posm) {
  int bid = blockIdx.x;
  int t = threadIdx.x;
  if (bid < 2052) {
    int i = bid * 256 + t;
    if (i < 65536)       wqkv[i]            = f2bf(qw[i]);
    else if (i < 196608) wqkv[i]            = f2bf(kvw[i - 65536]);
    else if (i < 262144) wproj[i - 196608]  = f2bf(pjw[i - 196608]);
    else if (i < 393216) wfc1[i - 262144]   = f2bf(f1w[i - 262144]);
    else if (i < 524288) wfc2[i - 393216]   = f2bf(f2w[i - 393216]);
    else if (i < 524544) bqkv[i - 524288]   = qb[i - 524288];
    else if (i < 525056) bqkv[i - 524288]   = kvb[i - 524544];
    else if (i < 525312) bkh[i - 525056]    = f2h(bk[i - 525056]);
  } else if (bid < 6148) {
    int row = (bid - 2052) * 4 + (t >> 6);
    int l = t & 63;
    float4 v = *(const float4*)(feat + (size_t)row * kC + l * 4);
    float s  = v.x + v.y + v.z + v.w;
    float s2 = v.x * v.x + v.y * v.y + v.z * v.z + v.w * v.w;
#pragma unroll
    for (int d = 1; d < 64; d <<= 1) {
      s  += __shfl_xor(s, d, 64);
      s2 += __shfl_xor(s2, d, 64);
    }
    float mu = s * (1.0f / kC);
    float rstd = rsqrtf(s2 * (1.0f / kC) - mu * mu + 1e-5f);
    float4 wv = *(const float4*)(n1w + l * 4);
    float4 bv = *(const float4*)(n1b + l * 4);
    uint2 ov;
    ov.x = ((unsigned int)f2bf((v.y - mu) * rstd * wv.y + bv.y) << 16) |
           f2bf((v.x - mu) * rstd * wv.x + bv.x);
    ov.y = ((unsigned int)f2bf((v.w - mu) * rstd * wv.w + bv.w) << 16) |
           f2bf((v.z - mu) * rstd * wv.z + bv.z);
    *(uint2*)(xln + (size_t)row * kC + l * 4) = ov;
  } else {
    int i = (bid - 6148) * 256 + t;
    int row = i >> 8, m = (i >> 3) & 31, h = i & 7;
    int idx = pe_idx[(size_t)row * 32 + m];
    float acc = pe_b[h];
#pragma unroll
    for (int f = 0; f < 5; ++f)
      acc += pre_table[idx * 5 + f] * pe_w[h * 5 + f];
    acc += (1.0f - cmask[(size_t)row * 32 + m]) * -100.0f;
    posm[(size_t)row * 256 + h * 32 + m] = f2h(acc);
  }
}

// ---- bf16 MFMA GEMM (QKV only): BM=64, BN=256, 8 waves, BK=64 dbuf ---------
template <int EPI, int KDIM>
__global__ __launch_bounds__(512) void gemm64(
    const unsigned short* __restrict__ A, const unsigned short* __restrict__ Wt,
    const float* __restrict__ bias, void* __restrict__ o1,
    unsigned short* __restrict__ o2, unsigned short* __restrict__ o3) {
  __shared__ alignas(16) unsigned short smem[40960];
  unsigned short* As0 = smem;
  unsigned short* Bs0 = smem + 8192;
  int t = threadIdx.x;
  int w = t >> 6, l = t & 63;
  int bm = blockIdx.x * 64, bn = blockIdx.y * 256;

  f32x4 acc[4][2] = {};

  const size_t aoff = (size_t)(bm + w * 8 + (l >> 3)) * KDIM + (l & 7) * 8;
  const size_t boff = (size_t)(bn + w * 32 + (l >> 3)) * KDIM + (l & 7) * 8;
  const int lr = l & 15, lk = l >> 4;

#define STAGE_T(buf, k0)                                                      \
  do {                                                                        \
    GLOAD16(A + aoff + (k0), As0 + (buf)*4096 + w * 512 + l * 8);             \
    GLOAD16(Wt + boff + (k0), Bs0 + (buf)*16384 + w * 2048 + l * 8);          \
    GLOAD16(Wt + boff + (k0) + (size_t)8 * KDIM,                              \
            Bs0 + (buf)*16384 + w * 2048 + 512 + l * 8);                      \
    GLOAD16(Wt + boff + (k0) + (size_t)16 * KDIM,                             \
            Bs0 + (buf)*16384 + w * 2048 + 1024 + l * 8);                     \
    GLOAD16(Wt + boff + (k0) + (size_t)24 * KDIM,                             \
            Bs0 + (buf)*16384 + w * 2048 + 1536 + l * 8);                     \
  } while (0)

  auto compute = [&](int buf) {
#pragma unroll
    for (int kk = 0; kk < 2; ++kk) {
      bf16x8 af[4], bfr[2];
#pragma unroll
      for (int mi = 0; mi < 4; ++mi)
        af[mi] = *(const bf16x8*)(As0 + buf * 4096 + (mi * 16 + lr) * 64 +
                                  kk * 32 + lk * 8);
#pragma unroll
      for (int ni = 0; ni < 2; ++ni)
        bfr[ni] = *(const bf16x8*)(Bs0 + buf * 16384 +
                                   (w * 32 + ni * 16 + lr) * 64 + kk * 32 +
                                   lk * 8);
#pragma unroll
      for (int mi = 0; mi < 4; ++mi)
#pragma unroll
        for (int ni = 0; ni < 2; ++ni)
          acc[mi][ni] = __builtin_amdgcn_mfma_f32_16x16x32_bf16(
              af[mi], bfr[ni], acc[mi][ni], 0, 0, 0);
    }
  };

  STAGE_T(0, 0);
  __syncthreads();
  int cur = 0;
#pragma unroll
  for (int k0 = 64; k0 < KDIM; k0 += 64) {
    STAGE_T(cur ^ 1, k0);
    compute(cur);
    __syncthreads();
    cur ^= 1;
  }
  compute(cur);

#pragma unroll
  for (int mi = 0; mi < 4; ++mi) {
#pragma unroll
    for (int ni = 0; ni < 2; ++ni) {
      int col = bn + w * 32 + ni * 16 + lr;
      float bv = bias[col];
#pragma unroll
      for (int j = 0; j < 4; ++j) {
        int rg = bm + mi * 16 + lk * 4 + j;
        float x = acc[mi][ni][j] + bv;
        if (col < 256) {
          ((unsigned short*)o1)[(size_t)rg * 256 + col] = f2h(x * kScale);
        } else {
          int c = col - 256;
          int h = c >> 6, sbit = (c >> 5) & 1, ch = c & 31;
          unsigned short* dst = sbit ? o3 : o2;
          dst[(size_t)rg * 256 + h * 32 + ch] = f2h(x);
        }
      }
    }
  }
#undef STAGE_T
}

// ---- fused proj+residual+LN2+fc1+gelu+fc2+residual, 64 rows per block ------
__global__ __launch_bounds__(512) void mlp_fused(
    const unsigned short* __restrict__ A,    // attn_out bf16 [16384][256]
    const unsigned short* __restrict__ Wp,   // wproj bf16 [256][256]
    const float* __restrict__ pbias,         // proj_b
    const float* __restrict__ feat,          // residual f32
    const float* __restrict__ w2, const float* __restrict__ b2,
    const unsigned short* __restrict__ W1, const float* __restrict__ b1,
    const unsigned short* __restrict__ W2, const float* __restrict__ b2f,
    float* __restrict__ outp) {
  __shared__ alignas(16) unsigned short sm[66560];
  int t = threadIdx.x;
  int w = t >> 6, l = t & 63;
  int bm = blockIdx.x * 64;
  const int lr = l & 15, lk = l >> 4;

  // ---------------- proj ----------------
  f32x4 accp[4][2] = {};
  {
    const size_t aoff = (size_t)(bm + w * 8 + (l >> 3)) * 256 + (l & 7) * 8;
    const size_t boff = (size_t)(w * 32 + (l >> 3)) * 256 + (l & 7) * 8;
#define PSTAGE(buf, k0)                                                       \
  do {                                                                        \
    GLOAD16(A + aoff + (k0), sm + (buf)*4096 + w * 512 + l * 8);              \
    GLOAD16(Wp + boff + (k0), sm + 8192 + (buf)*16384 + w * 2048 + l * 8);    \
    GLOAD16(Wp + boff + (k0) + (size_t)2048,                                  \
            sm + 8192 + (buf)*16384 + w * 2048 + 512 + l * 8);                \
    GLOAD16(Wp + boff + (k0) + (size_t)4096,                                  \
            sm + 8192 + (buf)*16384 + w * 2048 + 1024 + l * 8);               \
    GLOAD16(Wp + boff + (k0) + (size_t)6144,                                  \
            sm + 8192 + (buf)*16384 + w * 2048 + 1536 + l * 8);               \
  } while (0)
    auto computeP = [&](int buf) {
#pragma unroll
      for (int kk = 0; kk < 2; ++kk) {
        bf16x8 af[4], bfr[2];
#pragma unroll
        for (int mi = 0; mi < 4; ++mi)
          af[mi] = *(const bf16x8*)(sm + buf * 4096 + (mi * 16 + lr) * 64 +
                                    kk * 32 + lk * 8);
#pragma unroll
        for (int ni = 0; ni < 2; ++ni)
          bfr[ni] = *(const bf16x8*)(sm + 8192 + buf * 16384 +
                                     (w * 32 + ni * 16 + lr) * 64 + kk * 32 +
                                     lk * 8);
#pragma unroll
        for (int mi = 0; mi < 4; ++mi)
#pragma unroll
          for (int ni = 0; ni < 2; ++ni)
            accp[mi][ni] = __builtin_amdgcn_mfma_f32_16x16x32_bf16(
                af[mi], bfr[ni], accp[mi][ni], 0, 0, 0);
      }
    };
    PSTAGE(0, 0);
    __syncthreads();
    int cur = 0;
#pragma unroll
    for (int k0 = 64; k0 < 256; k0 += 64) {
      PSTAGE(cur ^ 1, k0);
      computeP(cur);
      __syncthreads();
      cur ^= 1;
    }
    computeP(cur);
#undef PSTAGE
  }

  // ---------------- x = proj + bias + feat (regs + LDS) ----------------
  f32x4 xr[4][2];
  float* xs = (float*)sm;
  __syncthreads();
#pragma unroll
  for (int mi = 0; mi < 4; ++mi) {
#pragma unroll
    for (int ni = 0; ni < 2; ++ni) {
      int c = w * 32 + ni * 16 + lr;
      float bv = pbias[c];
#pragma unroll
      for (int j = 0; j < 4; ++j) {
        int rl = mi * 16 + lk * 4 + j;
        float x = accp[mi][ni][j] + bv + feat[(size_t)(bm + rl) * 256 + c];
        xr[mi][ni][j] = x;
        xs[rl * 260 + c] = x;
      }
    }
  }
  __syncthreads();

  // ---------------- LN2 -> yln (LDS bf16 [64][264] @49664) ----------------
  {
    int r = t >> 3, sub = t & 7;
    float4 xv[8];
    float sx = 0.f, sxx = 0.f;
#pragma unroll
    for (int i = 0; i < 8; ++i) {
      xv[i] = *(const float4*)&xs[r * 260 + sub * 4 + i * 32];
      sx  += xv[i].x + xv[i].y + xv[i].z + xv[i].w;
      sxx += xv[i].x * xv[i].x + xv[i].y * xv[i].y + xv[i].z * xv[i].z +
             xv[i].w * xv[i].w;
    }
#pragma unroll
    for (int d = 1; d < 8; d <<= 1) {
      sx  += __shfl_xor(sx, d, 64);
      sxx += __shfl_xor(sxx, d, 64);
    }
    float mu = sx * (1.0f / 256.0f);
    float rstd = rsqrtf(sxx * (1.0f / 256.0f) - mu * mu + 1e-5f);
#pragma unroll
    for (int i = 0; i < 8; ++i) {
      int c = sub * 4 + i * 32;
      float4 wv = *(const float4*)(w2 + c);
      float4 bv = *(const float4*)(b2 + c);
      uint2 ov;
      ov.x = ((unsigned int)f2bf((xv[i].y - mu) * rstd * wv.y + bv.y) << 16) |
             f2bf((xv[i].x - mu) * rstd * wv.x + bv.x);
      ov.y = ((unsigned int)f2bf((xv[i].w - mu) * rstd * wv.w + bv.w) << 16) |
             f2bf((xv[i].z - mu) * rstd * wv.z + bv.z);
      *(uint2*)&sm[49664 + r * 264 + c] = ov;
    }
  }
  __syncthreads();

  // ---------------- fc1 + gelu -> h1 (LDS bf16 [64][520] @0) ----------------
  const int FB = 33280;
#define F1STAGE(buf, k0, c)                                                   \
  do {                                                                        \
    GLOAD16(W1 + (size_t)((c)*256 + w * 32 + (l >> 2)) * 256 + (k0) +         \
                (l & 3) * 8,                                                  \
            sm + FB + (buf)*8192 + w * 1024 + l * 8);                         \
    GLOAD16(W1 + (size_t)((c)*256 + w * 32 + 16 + (l >> 2)) * 256 + (k0) +    \
                (l & 3) * 8,                                                  \
            sm + FB + (buf)*8192 + w * 1024 + 512 + l * 8);                   \
  } while (0)
#pragma unroll
  for (int c = 0; c < 2; ++c) {
    f32x4 accf[4][2] = {};
    auto computeF1 = [&](int buf, int ka) {
      bf16x8 af[4], bfr[2];
#pragma unroll
      for (int mi = 0; mi < 4; ++mi)
        af[mi] =
            *(const bf16x8*)(sm + 49664 + (mi * 16 + lr) * 264 + ka + lk * 8);
#pragma unroll
      for (int ni = 0; ni < 2; ++ni)
        bfr[ni] = *(const bf16x8*)(sm + FB + buf * 8192 +
                                   (w * 32 + ni * 16 + lr) * 32 + lk * 8);
#pragma unroll
      for (int mi = 0; mi < 4; ++mi)
#pragma unroll
        for (int ni = 0; ni < 2; ++ni)
          accf[mi][ni] = __builtin_amdgcn_mfma_f32_16x16x32_bf16(
              af[mi], bfr[ni], accf[mi][ni], 0, 0, 0);
    };
    F1STAGE(0, 0, c);
    __syncthreads();
    int cur = 0;
#pragma unroll
    for (int k0 = 32; k0 < 256; k0 += 32) {
      F1STAGE(cur ^ 1, k0, c);
      computeF1(cur, k0 - 32);
      __syncthreads();
      cur ^= 1;
    }
    computeF1(cur, 224);
    __syncthreads();
#pragma unroll
    for (int mi = 0; mi < 4; ++mi) {
#pragma unroll
      for (int ni = 0; ni < 2; ++ni) {
        int colg = c * 256 + w * 32 + ni * 16 + lr;
        float bv = b1[colg];
#pragma unroll
        for (int j = 0; j < 4; ++j) {
          float x = accf[mi][ni][j] + bv;
          float g = 0.5f * x * (1.0f + erff(x * 0.70710678118654752f));
          sm[(mi * 16 + lk * 4 + j) * 520 + colg] = f2bf(g);
        }
      }
    }
  }
#undef F1STAGE
  __syncthreads();

  // ---------------- fc2 (K=512, BK=64) + residual -> out ----------------
  f32x4 acc2[4][2] = {};
#define F2STAGE(buf, k0)                                                      \
  do {                                                                        \
    GLOAD16(W2 + (size_t)(w * 32 + (l >> 3)) * 512 + (k0) + (l & 7) * 8,      \
            sm + FB + (buf)*16384 + w * 2048 + l * 8);                        \
    GLOAD16(W2 + (size_t)(w * 32 + 8 + (l >> 3)) * 512 + (k0) + (l & 7) * 8,  \
            sm + FB + (buf)*16384 + w * 2048 + 512 + l * 8);                  \
    GLOAD16(W2 + (size_t)(w * 32 + 16 + (l >> 3)) * 512 + (k0) + (l & 7) * 8, \
            sm + FB + (buf)*16384 + w * 2048 + 1024 + l * 8);                 \
    GLOAD16(W2 + (size_t)(w * 32 + 24 + (l >> 3)) * 512 + (k0) + (l & 7) * 8, \
            sm + FB + (buf)*16384 + w * 2048 + 1536 + l * 8);                 \
  } while (0)
  {
    auto computeF2 = [&](int buf, int ka) {
#pragma unroll
      for (int kk = 0; kk < 2; ++kk) {
        bf16x8 af[4], bfr[2];
#pragma unroll
        for (int mi = 0; mi < 4; ++mi)
          af[mi] = *(const bf16x8*)(sm + (mi * 16 + lr) * 520 + ka + kk * 32 +
                                    lk * 8);
#pragma unroll
        for (int ni = 0; ni < 2; ++ni)
          bfr[ni] = *(const bf16x8*)(sm + FB + buf * 16384 +
                                     (w * 32 + ni * 16 + lr) * 64 + kk * 32 +
                                     lk * 8);
#pragma unroll
        for (int mi = 0; mi < 4; ++mi)
#pragma unroll
          for (int ni = 0; ni < 2; ++ni)
            acc2[mi][ni] = __builtin_amdgcn_mfma_f32_16x16x32_bf16(
                af[mi], bfr[ni], acc2[mi][ni], 0, 0, 0);
      }
    };
    F2STAGE(0, 0);
    __syncthreads();
    int cur = 0;
#pragma unroll
    for (int k0 = 64; k0 < 512; k0 += 64) {
      F2STAGE(cur ^ 1, k0);
      computeF2(cur, k0 - 64);
      __syncthreads();
      cur ^= 1;
    }
    computeF2(cur, 448);
  }
#undef F2STAGE

#pragma unroll
  for (int mi = 0; mi < 4; ++mi) {
#pragma unroll
    for (int ni = 0; ni < 2; ++ni) {
      int col = w * 32 + ni * 16 + lr;
      float bv = b2f[col];
#pragma unroll
      for (int j = 0; j < 4; ++j) {
        int rg = bm + mi * 16 + lk * 4 + j;
        outp[(size_t)rg * 256 + col] = xr[mi][ni][j] + acc2[mi][ni][j] + bv;
      }
    }
  }
}

// -------- Attention (r13/r14): XCD-partitioned, f16, fma_mix ----------------
__global__ __launch_bounds__(256) void attn_kernel(
    const unsigned short* __restrict__ q, const unsigned short* __restrict__ k,
    const unsigned short* __restrict__ v, const int* __restrict__ member_idx,
    const unsigned short* __restrict__ posm,
    const unsigned short* __restrict__ bkh, const float* __restrict__ blank_v,
    unsigned short* __restrict__ outp) {
  int t = threadIdx.x;
  int w = t >> 6, l = t & 63;
  int bid = blockIdx.x;
  int part = bid & 7;
  int bb = part >> 2, hg = part & 3;
  int row = bb * kN + (bid >> 3) * 4 + w;
  const unsigned int kvbyte = (unsigned int)bb * (kN * 512u);

  __shared__ float        aw[4][2][36];
  __shared__ unsigned int offs[4][32];
  __shared__ float        posl[4][2][32];

  {
    int m = l & 31, hloc = l >> 5;
    posl[w][hloc][m] = h2f(posm[(size_t)row * 256 + hg * 64 + l]);
    if (l < 32)
      offs[w][l] =
          kvbyte + (unsigned int)member_idx[(size_t)row * 32 + l] * 512u;
  }
  __syncthreads();

  const int m8 = l >> 3, ch = l & 7;
  const int hsel = ch >> 2;

  h8 qv8 = *(const h8*)(q + (size_t)row * 256 + hg * 64 + ch * 8);

  float lg[4];
#pragma unroll
  for (int i = 0; i < 4; ++i) {
    int mi = i * 8 + m8;
    const char* kp = (const char*)k + offs[w][mi] + hg * 128 + ch * 16;
    h8 kv = *(const h8*)kp;
    float p = 0.f;
#pragma unroll
    for (int e = 0; e < 8; ++e) p = fmaf((float)qv8[e], (float)kv[e], p);
    p += __shfl_xor(p, 1, 64);
    p += __shfl_xor(p, 2, 64);
    lg[i] = p + posl[w][hsel][mi];
  }

  float bl = 0.f;
  {
    h8 bk8 = *(const h8*)(bkh + hg * 64 + ch * 8);
#pragma unroll
    for (int e = 0; e < 8; ++e) bl = fmaf((float)qv8[e], (float)bk8[e], bl);
    bl += __shfl_xor(bl, 1, 64);
    bl += __shfl_xor(bl, 2, 64);
    bl = fminf(fmaxf(bl, -5.0f), 5.0f);
  }

  float mx = fmaxf(fmaxf(lg[0], lg[1]), fmaxf(lg[2], lg[3]));
  mx = fmaxf(mx, __shfl_xor(mx, 8, 64));
  mx = fmaxf(mx, __shfl_xor(mx, 16, 64));
  mx = fmaxf(mx, __shfl_xor(mx, 32, 64));
  mx = fmaxf(mx, bl);
  float e4[4], s = 0.f;
#pragma unroll
  for (int i = 0; i < 4; ++i) { e4[i] = __expf(lg[i] - mx); s += e4[i]; }
  s += __shfl_xor(s, 8, 64);
  s += __shfl_xor(s, 16, 64);
  s += __shfl_xor(s, 32, 64);
  float eb = __expf(bl - mx);
  s += eb;
  float inv = __builtin_amdgcn_rcpf(s);
  if ((ch & 3) == 0) {
#pragma unroll
    for (int i = 0; i < 4; ++i) aw[w][hsel][i * 8 + m8] = e4[i] * inv;
    if (m8 == 0) aw[w][hsel][32] = eb * inv;
  }
  __syncthreads();

  const int hp = l >> 5, sq = (l >> 3) & 3, c8 = l & 7;
  const char* vb = (const char*)v + (hg * 2 + hp) * 64 + c8 * 8;
  float a0 = 0.f, a1 = 0.f, a2 = 0.f, a3 = 0.f;
#pragma unroll
  for (int i = 0; i < 8; ++i) {
    int mm = sq * 8 + i;
    float a = aw[w][hp][mm];
    h4 u = *(const h4*)(vb + offs[w][mm]);
    a0 = fmaf(a, (float)u[0], a0);
    a1 = fmaf(a, (float)u[1], a1);
    a2 = fmaf(a, (float)u[2], a2);
    a3 = fmaf(a, (float)u[3], a3);
  }
  a0 += __shfl_xor(a0, 8, 64);  a1 += __shfl_xor(a1, 8, 64);
  a2 += __shfl_xor(a2, 8, 64);  a3 += __shfl_xor(a3, 8, 64);
  a0 += __shfl_xor(a0, 16, 64); a1 += __shfl_xor(a1, 16, 64);
  a2 += __shfl_xor(a2, 16, 64); a3 += __shfl_xor(a3, 16, 64);
  if (sq == 0) {
    float ab = aw[w][hp][32];
    int c = (hg * 2 + hp) * 32 + c8 * 4;
    float4 bv = *(const float4*)(blank_v + c);
    a0 = fmaf(ab, bv.x, a0);
    a1 = fmaf(ab, bv.y, a1);
    a2 = fmaf(ab, bv.z, a2);
    a3 = fmaf(ab, bv.w, a3);
    uint2 o;
    o.x = ((unsigned int)f2bf(a1) << 16) | f2bf(a0);
    o.y = ((unsigned int)f2bf(a3) << 16) | f2bf(a2);
    *(uint2*)(outp + (size_t)row * 256 + c) = o;
  }
}

extern "C" void kernel_launch(void* const* d_in, const int* in_sizes, int n_in,
                              void* d_out, int out_size, void* d_ws, size_t ws_size,
                              hipStream_t stream) {
  const float* feat       = (const float*)d_in[0];
  const int*   member_idx = (const int*)d_in[1];
  const float* cmask      = (const float*)d_in[2];
  const int*   pe_idx     = (const int*)d_in[3];
  const float* pre_table  = (const float*)d_in[5];
  const float* n1w        = (const float*)d_in[6];
  const float* n1b        = (const float*)d_in[7];
  const float* q_w        = (const float*)d_in[8];
  const float* q_b        = (const float*)d_in[9];
  const float* kv_w       = (const float*)d_in[10];
  const float* kv_b       = (const float*)d_in[11];
  const float* blank_k    = (const float*)d_in[12];
  const float* blank_v    = (const float*)d_in[13];
  const float* pe_w       = (const float*)d_in[14];
  const float* pe_b       = (const float*)d_in[15];
  const float* proj_w     = (const float*)d_in[16];
  const float* proj_b     = (const float*)d_in[17];
  const float* n2w        = (const float*)d_in[18];
  const float* n2b        = (const float*)d_in[19];
  const float* fc1_w      = (const float*)d_in[20];
  const float* fc1_b      = (const float*)d_in[21];
  const float* fc2_w      = (const float*)d_in[22];
  const float* fc2_b      = (const float*)d_in[23];

  float* out = (float*)d_out;
  unsigned char* ws = (unsigned char*)d_ws;

  unsigned short* xln   = (unsigned short*)(ws + 0);           // 8 MB, later attn_out
  unsigned short* q_buf = (unsigned short*)(ws + 8388608);     // 8 MB f16
  unsigned short* k_buf = (unsigned short*)(ws + 16777216);    // 8 MB f16
  unsigned short* v_buf = (unsigned short*)(ws + 25165824);    // 8 MB f16
  unsigned short* wqkv  = (unsigned short*)(ws + 33554432);    // 384 KB
  unsigned short* wproj = (unsigned short*)(ws + 33947648);    // 128 KB
  unsigned short* wfc1  = (unsigned short*)(ws + 34078720);    // 256 KB
  unsigned short* wfc2  = (unsigned short*)(ws + 34340864);    // 256 KB
  float*          bqkv  = (float*)(ws + 34603008);             // 3 KB
  unsigned short* bkh   = (unsigned short*)(ws + 34606080);    // 512 B
  unsigned short* attn_out = xln;
  unsigned short* posm  = (unsigned short*)out;  // d_out dead until mlp_fused

  prep_kernel<<<22532, 256, 0, stream>>>(
      q_w, kv_w, proj_w, fc1_w, fc2_w, q_b, kv_b, blank_k, feat, n1w, n1b,
      pe_idx, pre_table, pe_w, pe_b, cmask, wqkv, wproj, wfc1, wfc2, bqkv,
      bkh, xln, posm);

  gemm64<0, 256><<<dim3(kRowsTotal / 64, 3), 512, 0, stream>>>(
      xln, wqkv, bqkv, q_buf, k_buf, v_buf);

  attn_kernel<<<kRowsTotal, 256, 0, stream>>>(
      q_buf, k_buf, v_buf, member_idx, posm, bkh, blank_v, attn_out);

  mlp_fused<<<kRowsTotal / 64, 512, 0, stream>>>(
      attn_out, wproj, proj_b, feat, n2w, n2b, wfc1, fc1_b, wfc2, fc2_b, out);
}

// Round 18
// 105.428 us; speedup vs baseline: 1.1538x; 1.0342x over previous
//
#include <hip/hip_runtime.h>
#include <math.h>

namespace {
constexpr int kN    = 8192;
constexpr int kC    = 256;
constexpr int kRowsTotal = 2 * kN;  // B*N = 16384
constexpr float kScale = 0.17677669529663687f;  // 32^-0.5
}

typedef __attribute__((ext_vector_type(8))) short bf16x8;
typedef __attribute__((ext_vector_type(4))) float f32x4;
typedef _Float16 h8 __attribute__((ext_vector_type(8)));
typedef _Float16 h4 __attribute__((ext_vector_type(4)));

__device__ __forceinline__ unsigned short f2bf(float f) {
  unsigned int u = __float_as_uint(f);
  u += 0x7fffu + ((u >> 16) & 1u);   // round-to-nearest-even
  return (unsigned short)(u >> 16);
}
__device__ __forceinline__ unsigned short f2h(float f) {
  _Float16 h = (_Float16)f;
  unsigned short u;
  __builtin_memcpy(&u, &h, 2);
  return u;
}
__device__ __forceinline__ float h2f(unsigned short u) {
  _Float16 h;
  __builtin_memcpy(&h, &u, 2);
  return (float)h;
}

// wave-internal LDS sync (all LDS state in attn is wave-private):
// drain this wave's ds ops, and fence the scheduler (guide rule #18).
#define WAVE_SYNC()                                        \
  do {                                                     \
    asm volatile("s_waitcnt lgkmcnt(0)" ::: "memory");     \
    __builtin_amdgcn_sched_barrier(0);                     \
  } while (0)

#define GLOAD16(g, l)                                                   \
  __builtin_amdgcn_global_load_lds(                                     \
      (const __attribute__((address_space(1))) void*)(g),               \
      (__attribute__((address_space(3))) void*)(l), 16, 0, 0)

// ---- prep: weights cast (bid<2052) | LN1 (bid<6148) | posm (else) ----------
__global__ __launch_bounds__(256) void prep_kernel(
    const float* __restrict__ qw, const float* __restrict__ kvw,
    const float* __restrict__ pjw, const float* __restrict__ f1w,
    const float* __restrict__ f2w, const float* __restrict__ qb,
    const float* __restrict__ kvb, const float* __restrict__ bk,
    const float* __restrict__ feat, const float* __restrict__ n1w,
    const float* __restrict__ n1b, const int* __restrict__ pe_idx,
    const float* __restrict__ pre_table, const float* __restrict__ pe_w,
    const float* __restrict__ pe_b, const float* __restrict__ cmask,
    unsigned short* __restrict__ wqkv, unsigned short* __restrict__ wproj,
    unsigned short* __restrict__ wfc1, unsigned short* __restrict__ wfc2,
    float* __restrict__ bqkv, unsigned short* __restrict__ bkh,
    unsigned short* __restrict__ xln, unsigned short* __restrict__ posm) {
  int bid = blockIdx.x;
  int t = threadIdx.x;
  if (bid < 2052) {
    int i = bid * 256 + t;
    if (i < 65536)       wqkv[i]            = f2bf(qw[i]);
    else if (i < 196608) wqkv[i]            = f2bf(kvw[i - 65536]);
    else if (i < 262144) wproj[i - 196608]  = f2bf(pjw[i - 196608]);
    else if (i < 393216) wfc1[i - 262144]   = f2bf(f1w[i - 262144]);
    else if (i < 524288) wfc2[i - 393216]   = f2bf(f2w[i - 393216]);
    else if (i < 524544) bqkv[i - 524288]   = qb[i - 524288];
    else if (i < 525056) bqkv[i - 524288]   = kvb[i - 524544];
    else if (i < 525312) bkh[i - 525056]    = f2h(bk[i - 525056]);
  } else if (bid < 6148) {
    int row = (bid - 2052) * 4 + (t >> 6);
    int l = t & 63;
    float4 v = *(const float4*)(feat + (size_t)row * kC + l * 4);
    float s  = v.x + v.y + v.z + v.w;
    float s2 = v.x * v.x + v.y * v.y + v.z * v.z + v.w * v.w;
#pragma unroll
    for (int d = 1; d < 64; d <<= 1) {
      s  += __shfl_xor(s, d, 64);
      s2 += __shfl_xor(s2, d, 64);
    }
    float mu = s * (1.0f / kC);
    float rstd = rsqrtf(s2 * (1.0f / kC) - mu * mu + 1e-5f);
    float4 wv = *(const float4*)(n1w + l * 4);
    float4 bv = *(const float4*)(n1b + l * 4);
    uint2 ov;
    ov.x = ((unsigned int)f2bf((v.y - mu) * rstd * wv.y + bv.y) << 16) |
           f2bf((v.x - mu) * rstd * wv.x + bv.x);
    ov.y = ((unsigned int)f2bf((v.w - mu) * rstd * wv.w + bv.w) << 16) |
           f2bf((v.z - mu) * rstd * wv.z + bv.z);
    *(uint2*)(xln + (size_t)row * kC + l * 4) = ov;
  } else {
    int i = (bid - 6148) * 256 + t;
    int row = i >> 8, m = (i >> 3) & 31, h = i & 7;
    int idx = pe_idx[(size_t)row * 32 + m];
    float acc = pe_b[h];
#pragma unroll
    for (int f = 0; f < 5; ++f)
      acc += pre_table[idx * 5 + f] * pe_w[h * 5 + f];
    acc += (1.0f - cmask[(size_t)row * 32 + m]) * -100.0f;
    posm[(size_t)row * 256 + h * 32 + m] = f2h(acc);
  }
}

// ---- bf16 MFMA GEMM (QKV only): BM=64, BN=256, 8 waves, BK=64 dbuf ---------
template <int EPI, int KDIM>
__global__ __launch_bounds__(512) void gemm64(
    const unsigned short* __restrict__ A, const unsigned short* __restrict__ Wt,
    const float* __restrict__ bias, void* __restrict__ o1,
    unsigned short* __restrict__ o2, unsigned short* __restrict__ o3) {
  __shared__ alignas(16) unsigned short smem[40960];
  unsigned short* As0 = smem;
  unsigned short* Bs0 = smem + 8192;
  int t = threadIdx.x;
  int w = t >> 6, l = t & 63;
  int bm = blockIdx.x * 64, bn = blockIdx.y * 256;

  f32x4 acc[4][2] = {};

  const size_t aoff = (size_t)(bm + w * 8 + (l >> 3)) * KDIM + (l & 7) * 8;
  const size_t boff = (size_t)(bn + w * 32 + (l >> 3)) * KDIM + (l & 7) * 8;
  const int lr = l & 15, lk = l >> 4;

#define STAGE_T(buf, k0)                                                      \
  do {                                                                        \
    GLOAD16(A + aoff + (k0), As0 + (buf)*4096 + w * 512 + l * 8);             \
    GLOAD16(Wt + boff + (k0), Bs0 + (buf)*16384 + w * 2048 + l * 8);          \
    GLOAD16(Wt + boff + (k0) + (size_t)8 * KDIM,                              \
            Bs0 + (buf)*16384 + w * 2048 + 512 + l * 8);                      \
    GLOAD16(Wt + boff + (k0) + (size_t)16 * KDIM,                             \
            Bs0 + (buf)*16384 + w * 2048 + 1024 + l * 8);                     \
    GLOAD16(Wt + boff + (k0) + (size_t)24 * KDIM,                             \
            Bs0 + (buf)*16384 + w * 2048 + 1536 + l * 8);                     \
  } while (0)

  auto compute = [&](int buf) {
#pragma unroll
    for (int kk = 0; kk < 2; ++kk) {
      bf16x8 af[4], bfr[2];
#pragma unroll
      for (int mi = 0; mi < 4; ++mi)
        af[mi] = *(const bf16x8*)(As0 + buf * 4096 + (mi * 16 + lr) * 64 +
                                  kk * 32 + lk * 8);
#pragma unroll
      for (int ni = 0; ni < 2; ++ni)
        bfr[ni] = *(const bf16x8*)(Bs0 + buf * 16384 +
                                   (w * 32 + ni * 16 + lr) * 64 + kk * 32 +
                                   lk * 8);
#pragma unroll
      for (int mi = 0; mi < 4; ++mi)
#pragma unroll
        for (int ni = 0; ni < 2; ++ni)
          acc[mi][ni] = __builtin_amdgcn_mfma_f32_16x16x32_bf16(
              af[mi], bfr[ni], acc[mi][ni], 0, 0, 0);
    }
  };

  STAGE_T(0, 0);
  __syncthreads();
  int cur = 0;
#pragma unroll
  for (int k0 = 64; k0 < KDIM; k0 += 64) {
    STAGE_T(cur ^ 1, k0);
    compute(cur);
    __syncthreads();
    cur ^= 1;
  }
  compute(cur);

#pragma unroll
  for (int mi = 0; mi < 4; ++mi) {
#pragma unroll
    for (int ni = 0; ni < 2; ++ni) {
      int col = bn + w * 32 + ni * 16 + lr;
      float bv = bias[col];
#pragma unroll
      for (int j = 0; j < 4; ++j) {
        int rg = bm + mi * 16 + lk * 4 + j;
        float x = acc[mi][ni][j] + bv;
        if (col < 256) {
          ((unsigned short*)o1)[(size_t)rg * 256 + col] = f2h(x * kScale);
        } else {
          int c = col - 256;
          int h = c >> 6, sbit = (c >> 5) & 1, ch = c & 31;
          unsigned short* dst = sbit ? o3 : o2;
          dst[(size_t)rg * 256 + h * 32 + ch] = f2h(x);
        }
      }
    }
  }
#undef STAGE_T
}

// ---- fused proj+residual+LN2+fc1+gelu+fc2+residual, 64 rows per block ------
__global__ __launch_bounds__(512) void mlp_fused(
    const unsigned short* __restrict__ A,    // attn_out bf16 [16384][256]
    const unsigned short* __restrict__ Wp,   // wproj bf16 [256][256]
    const float* __restrict__ pbias,         // proj_b
    const float* __restrict__ feat,          // residual f32
    const float* __restrict__ w2, const float* __restrict__ b2,
    const unsigned short* __restrict__ W1, const float* __restrict__ b1,
    const unsigned short* __restrict__ W2, const float* __restrict__ b2f,
    float* __restrict__ outp) {
  __shared__ alignas(16) unsigned short sm[66560];
  int t = threadIdx.x;
  int w = t >> 6, l = t & 63;
  int bm = blockIdx.x * 64;
  const int lr = l & 15, lk = l >> 4;

  // ---------------- proj ----------------
  f32x4 accp[4][2] = {};
  {
    const size_t aoff = (size_t)(bm + w * 8 + (l >> 3)) * 256 + (l & 7) * 8;
    const size_t boff = (size_t)(w * 32 + (l >> 3)) * 256 + (l & 7) * 8;
#define PSTAGE(buf, k0)                                                       \
  do {                                                                        \
    GLOAD16(A + aoff + (k0), sm + (buf)*4096 + w * 512 + l * 8);              \
    GLOAD16(Wp + boff + (k0), sm + 8192 + (buf)*16384 + w * 2048 + l * 8);    \
    GLOAD16(Wp + boff + (k0) + (size_t)2048,                                  \
            sm + 8192 + (buf)*16384 + w * 2048 + 512 + l * 8);                \
    GLOAD16(Wp + boff + (k0) + (size_t)4096,                                  \
            sm + 8192 + (buf)*16384 + w * 2048 + 1024 + l * 8);               \
    GLOAD16(Wp + boff + (k0) + (size_t)6144,                                  \
            sm + 8192 + (buf)*16384 + w * 2048 + 1536 + l * 8);               \
  } while (0)
    auto computeP = [&](int buf) {
#pragma unroll
      for (int kk = 0; kk < 2; ++kk) {
        bf16x8 af[4], bfr[2];
#pragma unroll
        for (int mi = 0; mi < 4; ++mi)
          af[mi] = *(const bf16x8*)(sm + buf * 4096 + (mi * 16 + lr) * 64 +
                                    kk * 32 + lk * 8);
#pragma unroll
        for (int ni = 0; ni < 2; ++ni)
          bfr[ni] = *(const bf16x8*)(sm + 8192 + buf * 16384 +
                                     (w * 32 + ni * 16 + lr) * 64 + kk * 32 +
                                     lk * 8);
#pragma unroll
        for (int mi = 0; mi < 4; ++mi)
#pragma unroll
          for (int ni = 0; ni < 2; ++ni)
            accp[mi][ni] = __builtin_amdgcn_mfma_f32_16x16x32_bf16(
                af[mi], bfr[ni], accp[mi][ni], 0, 0, 0);
      }
    };
    PSTAGE(0, 0);
    __syncthreads();
    int cur = 0;
#pragma unroll
    for (int k0 = 64; k0 < 256; k0 += 64) {
      PSTAGE(cur ^ 1, k0);
      computeP(cur);
      __syncthreads();
      cur ^= 1;
    }
    computeP(cur);
#undef PSTAGE
  }

  // ---------------- x = proj + bias + feat (regs + LDS) ----------------
  f32x4 xr[4][2];
  float* xs = (float*)sm;
  __syncthreads();
#pragma unroll
  for (int mi = 0; mi < 4; ++mi) {
#pragma unroll
    for (int ni = 0; ni < 2; ++ni) {
      int c = w * 32 + ni * 16 + lr;
      float bv = pbias[c];
#pragma unroll
      for (int j = 0; j < 4; ++j) {
        int rl = mi * 16 + lk * 4 + j;
        float x = accp[mi][ni][j] + bv + feat[(size_t)(bm + rl) * 256 + c];
        xr[mi][ni][j] = x;
        xs[rl * 260 + c] = x;
      }
    }
  }
  __syncthreads();

  // ---------------- LN2 -> yln (LDS bf16 [64][264] @49664) ----------------
  {
    int r = t >> 3, sub = t & 7;
    float4 xv[8];
    float sx = 0.f, sxx = 0.f;
#pragma unroll
    for (int i = 0; i < 8; ++i) {
      xv[i] = *(const float4*)&xs[r * 260 + sub * 4 + i * 32];
      sx  += xv[i].x + xv[i].y + xv[i].z + xv[i].w;
      sxx += xv[i].x * xv[i].x + xv[i].y * xv[i].y + xv[i].z * xv[i].z +
             xv[i].w * xv[i].w;
    }
#pragma unroll
    for (int d = 1; d < 8; d <<= 1) {
      sx  += __shfl_xor(sx, d, 64);
      sxx += __shfl_xor(sxx, d, 64);
    }
    float mu = sx * (1.0f / 256.0f);
    float rstd = rsqrtf(sxx * (1.0f / 256.0f) - mu * mu + 1e-5f);
#pragma unroll
    for (int i = 0; i < 8; ++i) {
      int c = sub * 4 + i * 32;
      float4 wv = *(const float4*)(w2 + c);
      float4 bv = *(const float4*)(b2 + c);
      uint2 ov;
      ov.x = ((unsigned int)f2bf((xv[i].y - mu) * rstd * wv.y + bv.y) << 16) |
             f2bf((xv[i].x - mu) * rstd * wv.x + bv.x);
      ov.y = ((unsigned int)f2bf((xv[i].w - mu) * rstd * wv.w + bv.w) << 16) |
             f2bf((xv[i].z - mu) * rstd * wv.z + bv.z);
      *(uint2*)&sm[49664 + r * 264 + c] = ov;
    }
  }
  __syncthreads();

  // ---------------- fc1 + gelu -> h1 (LDS bf16 [64][520] @0) ----------------
  const int FB = 33280;
#define F1STAGE(buf, k0, c)                                                   \
  do {                                                                        \
    GLOAD16(W1 + (size_t)((c)*256 + w * 32 + (l >> 2)) * 256 + (k0) +         \
                (l & 3) * 8,                                                  \
            sm + FB + (buf)*8192 + w * 1024 + l * 8);                         \
    GLOAD16(W1 + (size_t)((c)*256 + w * 32 + 16 + (l >> 2)) * 256 + (k0) +    \
                (l & 3) * 8,                                                  \
            sm + FB + (buf)*8192 + w * 1024 + 512 + l * 8);                   \
  } while (0)
#pragma unroll
  for (int c = 0; c < 2; ++c) {
    f32x4 accf[4][2] = {};
    auto computeF1 = [&](int buf, int ka) {
      bf16x8 af[4], bfr[2];
#pragma unroll
      for (int mi = 0; mi < 4; ++mi)
        af[mi] =
            *(const bf16x8*)(sm + 49664 + (mi * 16 + lr) * 264 + ka + lk * 8);
#pragma unroll
      for (int ni = 0; ni < 2; ++ni)
        bfr[ni] = *(const bf16x8*)(sm + FB + buf * 8192 +
                                   (w * 32 + ni * 16 + lr) * 32 + lk * 8);
#pragma unroll
      for (int mi = 0; mi < 4; ++mi)
#pragma unroll
        for (int ni = 0; ni < 2; ++ni)
          accf[mi][ni] = __builtin_amdgcn_mfma_f32_16x16x32_bf16(
              af[mi], bfr[ni], accf[mi][ni], 0, 0, 0);
    };
    F1STAGE(0, 0, c);
    __syncthreads();
    int cur = 0;
#pragma unroll
    for (int k0 = 32; k0 < 256; k0 += 32) {
      F1STAGE(cur ^ 1, k0, c);
      computeF1(cur, k0 - 32);
      __syncthreads();
      cur ^= 1;
    }
    computeF1(cur, 224);
    __syncthreads();
#pragma unroll
    for (int mi = 0; mi < 4; ++mi) {
#pragma unroll
      for (int ni = 0; ni < 2; ++ni) {
        int colg = c * 256 + w * 32 + ni * 16 + lr;
        float bv = b1[colg];
#pragma unroll
        for (int j = 0; j < 4; ++j) {
          float x = accf[mi][ni][j] + bv;
          float g = 0.5f * x * (1.0f + erff(x * 0.70710678118654752f));
          sm[(mi * 16 + lk * 4 + j) * 520 + colg] = f2bf(g);
        }
      }
    }
  }
#undef F1STAGE
  __syncthreads();

  // ---------------- fc2 (K=512, BK=64) + residual -> out ----------------
  f32x4 acc2[4][2] = {};
#define F2STAGE(buf, k0)                                                      \
  do {                                                                        \
    GLOAD16(W2 + (size_t)(w * 32 + (l >> 3)) * 512 + (k0) + (l & 7) * 8,      \
            sm + FB + (buf)*16384 + w * 2048 + l * 8);                        \
    GLOAD16(W2 + (size_t)(w * 32 + 8 + (l >> 3)) * 512 + (k0) + (l & 7) * 8,  \
            sm + FB + (buf)*16384 + w * 2048 + 512 + l * 8);                  \
    GLOAD16(W2 + (size_t)(w * 32 + 16 + (l >> 3)) * 512 + (k0) + (l & 7) * 8, \
            sm + FB + (buf)*16384 + w * 2048 + 1024 + l * 8);                 \
    GLOAD16(W2 + (size_t)(w * 32 + 24 + (l >> 3)) * 512 + (k0) + (l & 7) * 8, \
            sm + FB + (buf)*16384 + w * 2048 + 1536 + l * 8);                 \
  } while (0)
  {
    auto computeF2 = [&](int buf, int ka) {
#pragma unroll
      for (int kk = 0; kk < 2; ++kk) {
        bf16x8 af[4], bfr[2];
#pragma unroll
        for (int mi = 0; mi < 4; ++mi)
          af[mi] = *(const bf16x8*)(sm + (mi * 16 + lr) * 520 + ka + kk * 32 +
                                    lk * 8);
#pragma unroll
        for (int ni = 0; ni < 2; ++ni)
          bfr[ni] = *(const bf16x8*)(sm + FB + buf * 16384 +
                                     (w * 32 + ni * 16 + lr) * 64 + kk * 32 +
                                     lk * 8);
#pragma unroll
        for (int mi = 0; mi < 4; ++mi)
#pragma unroll
          for (int ni = 0; ni < 2; ++ni)
            acc2[mi][ni] = __builtin_amdgcn_mfma_f32_16x16x32_bf16(
                af[mi], bfr[ni], acc2[mi][ni], 0, 0, 0);
      }
    };
    F2STAGE(0, 0);
    __syncthreads();
    int cur = 0;
#pragma unroll
    for (int k0 = 64; k0 < 512; k0 += 64) {
      F2STAGE(cur ^ 1, k0);
      computeF2(cur, k0 - 64);
      __syncthreads();
      cur ^= 1;
    }
    computeF2(cur, 448);
  }
#undef F2STAGE

#pragma unroll
  for (int mi = 0; mi < 4; ++mi) {
#pragma unroll
    for (int ni = 0; ni < 2; ++ni) {
      int col = w * 32 + ni * 16 + lr;
      float bv = b2f[col];
#pragma unroll
      for (int j = 0; j < 4; ++j) {
        int rg = bm + mi * 16 + lk * 4 + j;
        outp[(size_t)rg * 256 + col] = xr[mi][ni][j] + acc2[mi][ni][j] + bv;
      }
    }
  }
}

// -------- Attention: XCD-partitioned, f16, fma_mix; barrier-free waves ------
// All LDS state (aw/offs/posl) is wave-private ([w] indexed) -> replace
// __syncthreads with wave-internal lgkmcnt drain (WAVE_SYNC). Waves decouple.
__global__ __launch_bounds__(256) void attn_kernel(
    const unsigned short* __restrict__ q, const unsigned short* __restrict__ k,
    const unsigned short* __restrict__ v, const int* __restrict__ member_idx,
    const unsigned short* __restrict__ posm,
    const unsigned short* __restrict__ bkh, const float* __restrict__ blank_v,
    unsigned short* __restrict__ outp) {
  int t = threadIdx.x;
  int w = t >> 6, l = t & 63;
  int bid = blockIdx.x;
  int part = bid & 7;
  int bb = part >> 2, hg = part & 3;
  int row = bb * kN + (bid >> 3) * 4 + w;
  const unsigned int kvbyte = (unsigned int)bb * (kN * 512u);

  __shared__ float        aw[4][2][36];
  __shared__ unsigned int offs[4][32];
  __shared__ float        posl[4][2][32];

  {
    int m = l & 31, hloc = l >> 5;
    posl[w][hloc][m] = h2f(posm[(size_t)row * 256 + hg * 64 + l]);
    if (l < 32)
      offs[w][l] =
          kvbyte + (unsigned int)member_idx[(size_t)row * 32 + l] * 512u;
  }
  WAVE_SYNC();

  const int m8 = l >> 3, ch = l & 7;
  const int hsel = ch >> 2;

  h8 qv8 = *(const h8*)(q + (size_t)row * 256 + hg * 64 + ch * 8);

  float lg[4];
#pragma unroll
  for (int i = 0; i < 4; ++i) {
    int mi = i * 8 + m8;
    const char* kp = (const char*)k + offs[w][mi] + hg * 128 + ch * 16;
    h8 kv = *(const h8*)kp;
    float p = 0.f;
#pragma unroll
    for (int e = 0; e < 8; ++e) p = fmaf((float)qv8[e], (float)kv[e], p);
    p += __shfl_xor(p, 1, 64);
    p += __shfl_xor(p, 2, 64);
    lg[i] = p + posl[w][hsel][mi];
  }

  float bl = 0.f;
  {
    h8 bk8 = *(const h8*)(bkh + hg * 64 + ch * 8);
#pragma unroll
    for (int e = 0; e < 8; ++e) bl = fmaf((float)qv8[e], (float)bk8[e], bl);
    bl += __shfl_xor(bl, 1, 64);
    bl += __shfl_xor(bl, 2, 64);
    bl = fminf(fmaxf(bl, -5.0f), 5.0f);
  }

  float mx = fmaxf(fmaxf(lg[0], lg[1]), fmaxf(lg[2], lg[3]));
  mx = fmaxf(mx, __shfl_xor(mx, 8, 64));
  mx = fmaxf(mx, __shfl_xor(mx, 16, 64));
  mx = fmaxf(mx, __shfl_xor(mx, 32, 64));
  mx = fmaxf(mx, bl);
  float e4[4], s = 0.f;
#pragma unroll
  for (int i = 0; i < 4; ++i) { e4[i] = __expf(lg[i] - mx); s += e4[i]; }
  s += __shfl_xor(s, 8, 64);
  s += __shfl_xor(s, 16, 64);
  s += __shfl_xor(s, 32, 64);
  float eb = __expf(bl - mx);
  s += eb;
  float inv = __builtin_amdgcn_rcpf(s);
  if ((ch & 3) == 0) {
#pragma unroll
    for (int i = 0; i < 4; ++i) aw[w][hsel][i * 8 + m8] = e4[i] * inv;
    if (m8 == 0) aw[w][hsel][32] = eb * inv;
  }
  WAVE_SYNC();

  const int hp = l >> 5, sq = (l >> 3) & 3, c8 = l & 7;
  const char* vb = (const char*)v + (hg * 2 + hp) * 64 + c8 * 8;
  float a0 = 0.f, a1 = 0.f, a2 = 0.f, a3 = 0.f;
#pragma unroll
  for (int i = 0; i < 8; ++i) {
    int mm = sq * 8 + i;
    float a = aw[w][hp][mm];
    h4 u = *(const h4*)(vb + offs[w][mm]);
    a0 = fmaf(a, (float)u[0], a0);
    a1 = fmaf(a, (float)u[1], a1);
    a2 = fmaf(a, (float)u[2], a2);
    a3 = fmaf(a, (float)u[3], a3);
  }
  a0 += __shfl_xor(a0, 8, 64);  a1 += __shfl_xor(a1, 8, 64);
  a2 += __shfl_xor(a2, 8, 64);  a3 += __shfl_xor(a3, 8, 64);
  a0 += __shfl_xor(a0, 16, 64); a1 += __shfl_xor(a1, 16, 64);
  a2 += __shfl_xor(a2, 16, 64); a3 += __shfl_xor(a3, 16, 64);
  if (sq == 0) {
    float ab = aw[w][hp][32];
    int c = (hg * 2 + hp) * 32 + c8 * 4;
    float4 bv = *(const float4*)(blank_v + c);
    a0 = fmaf(ab, bv.x, a0);
    a1 = fmaf(ab, bv.y, a1);
    a2 = fmaf(ab, bv.z, a2);
    a3 = fmaf(ab, bv.w, a3);
    uint2 o;
    o.x = ((unsigned int)f2bf(a1) << 16) | f2bf(a0);
    o.y = ((unsigned int)f2bf(a3) << 16) | f2bf(a2);
    *(uint2*)(outp + (size_t)row * 256 + c) = o;
  }
}

extern "C" void kernel_launch(void* const* d_in, const int* in_sizes, int n_in,
                              void* d_out, int out_size, void* d_ws, size_t ws_size,
                              hipStream_t stream) {
  const float* feat       = (const float*)d_in[0];
  const int*   member_idx = (const int*)d_in[1];
  const float* cmask      = (const float*)d_in[2];
  const int*   pe_idx     = (const int*)d_in[3];
  const float* pre_table  = (const float*)d_in[5];
  const float* n1w        = (const float*)d_in[6];
  const float* n1b        = (const float*)d_in[7];
  const float* q_w        = (const float*)d_in[8];
  const float* q_b        = (const float*)d_in[9];
  const float* kv_w       = (const float*)d_in[10];
  const float* kv_b       = (const float*)d_in[11];
  const float* blank_k    = (const float*)d_in[12];
  const float* blank_v    = (const float*)d_in[13];
  const float* pe_w       = (const float*)d_in[14];
  const float* pe_b       = (const float*)d_in[15];
  const float* proj_w     = (const float*)d_in[16];
  const float* proj_b     = (const float*)d_in[17];
  const float* n2w        = (const float*)d_in[18];
  const float* n2b        = (const float*)d_in[19];
  const float* fc1_w      = (const float*)d_in[20];
  const float* fc1_b      = (const float*)d_in[21];
  const float* fc2_w      = (const float*)d_in[22];
  const float* fc2_b      = (const float*)d_in[23];

  float* out = (float*)d_out;
  unsigned char* ws = (unsigned char*)d_ws;

  unsigned short* xln   = (unsigned short*)(ws + 0);           // 8 MB, later attn_out
  unsigned short* q_buf = (unsigned short*)(ws + 8388608);     // 8 MB f16
  unsigned short* k_buf = (unsigned short*)(ws + 16777216);    // 8 MB f16
  unsigned short* v_buf = (unsigned short*)(ws + 25165824);    // 8 MB f16
  unsigned short* wqkv  = (unsigned short*)(ws + 33554432);    // 384 KB
  unsigned short* wproj = (unsigned short*)(ws + 33947648);    // 128 KB
  unsigned short* wfc1  = (unsigned short*)(ws + 34078720);    // 256 KB
  unsigned short* wfc2  = (unsigned short*)(ws + 34340864);    // 256 KB
  float*          bqkv  = (float*)(ws + 34603008);             // 3 KB
  unsigned short* bkh   = (unsigned short*)(ws + 34606080);    // 512 B
  unsigned short* attn_out = xln;
  unsigned short* posm  = (unsigned short*)out;  // d_out dead until mlp_fused

  prep_kernel<<<22532, 256, 0, stream>>>(
      q_w, kv_w, proj_w, fc1_w, fc2_w, q_b, kv_b, blank_k, feat, n1w, n1b,
      pe_idx, pre_table, pe_w, pe_b, cmask, wqkv, wproj, wfc1, wfc2, bqkv,
      bkh, xln, posm);

  gemm64<0, 256><<<dim3(kRowsTotal / 64, 3), 512, 0, stream>>>(
      xln, wqkv, bqkv, q_buf, k_buf, v_buf);

  attn_kernel<<<kRowsTotal, 256, 0, stream>>>(
      q_buf, k_buf, v_buf, member_idx, posm, bkh, blank_v, attn_out);

  mlp_fused<<<kRowsTotal / 64, 512, 0, stream>>>(
      attn_out, wproj, proj_b, feat, n2w, n2b, wfc1, fc1_b, wfc2, fc2_b, out);
}

// Round 19
// 105.325 us; speedup vs baseline: 1.1549x; 1.0010x over previous
//
#include <hip/hip_runtime.h>
#include <math.h>

namespace {
constexpr int kN    = 8192;
constexpr int kC    = 256;
constexpr int kRowsTotal = 2 * kN;  // B*N = 16384
constexpr float kScale = 0.17677669529663687f;  // 32^-0.5
}

typedef __attribute__((ext_vector_type(8))) short bf16x8;
typedef __attribute__((ext_vector_type(4))) float f32x4;
typedef _Float16 h8 __attribute__((ext_vector_type(8)));
typedef _Float16 h4 __attribute__((ext_vector_type(4)));
typedef _Float16 h2 __attribute__((ext_vector_type(2)));

__device__ __forceinline__ unsigned short f2bf(float f) {
  unsigned int u = __float_as_uint(f);
  u += 0x7fffu + ((u >> 16) & 1u);   // round-to-nearest-even
  return (unsigned short)(u >> 16);
}
__device__ __forceinline__ unsigned short f2h(float f) {
  _Float16 h = (_Float16)f;
  unsigned short u;
  __builtin_memcpy(&u, &h, 2);
  return u;
}
__device__ __forceinline__ float h2f(unsigned short u) {
  _Float16 h;
  __builtin_memcpy(&h, &u, 2);
  return (float)h;
}

#if __has_builtin(__builtin_amdgcn_fdot2)
__device__ __forceinline__ float fdot2f(h2 a, h2 b, float c) {
  return __builtin_amdgcn_fdot2(a, b, c, false);
}
#else
__device__ __forceinline__ float fdot2f(h2 a, h2 b, float c) {
  return fmaf((float)a[0], (float)b[0], fmaf((float)a[1], (float)b[1], c));
}
#endif

// wave-internal LDS sync (all LDS state in attn is wave-private):
// drain this wave's ds ops, and fence the scheduler (guide rule #18).
#define WAVE_SYNC()                                        \
  do {                                                     \
    asm volatile("s_waitcnt lgkmcnt(0)" ::: "memory");     \
    __builtin_amdgcn_sched_barrier(0);                     \
  } while (0)

#define GLOAD16(g, l)                                                   \
  __builtin_amdgcn_global_load_lds(                                     \
      (const __attribute__((address_space(1))) void*)(g),               \
      (__attribute__((address_space(3))) void*)(l), 16, 0, 0)

// ---- prep: weights cast (bid<2052) | LN1 (bid<6148) | posm (else) ----------
__global__ __launch_bounds__(256) void prep_kernel(
    const float* __restrict__ qw, const float* __restrict__ kvw,
    const float* __restrict__ pjw, const float* __restrict__ f1w,
    const float* __restrict__ f2w, const float* __restrict__ qb,
    const float* __restrict__ kvb, const float* __restrict__ bk,
    const float* __restrict__ feat, const float* __restrict__ n1w,
    const float* __restrict__ n1b, const int* __restrict__ pe_idx,
    const float* __restrict__ pre_table, const float* __restrict__ pe_w,
    const float* __restrict__ pe_b, const float* __restrict__ cmask,
    unsigned short* __restrict__ wqkv, unsigned short* __restrict__ wproj,
    unsigned short* __restrict__ wfc1, unsigned short* __restrict__ wfc2,
    float* __restrict__ bqkv, unsigned short* __restrict__ bkh,
    unsigned short* __restrict__ xln, unsigned short* __restrict__ posm) {
  int bid = blockIdx.x;
  int t = threadIdx.x;
  if (bid < 2052) {
    int i = bid * 256 + t;
    if (i < 65536)       wqkv[i]            = f2bf(qw[i]);
    else if (i < 196608) wqkv[i]            = f2bf(kvw[i - 65536]);
    else if (i < 262144) wproj[i - 196608]  = f2bf(pjw[i - 196608]);
    else if (i < 393216) wfc1[i - 262144]   = f2bf(f1w[i - 262144]);
    else if (i < 524288) wfc2[i - 393216]   = f2bf(f2w[i - 393216]);
    else if (i < 524544) bqkv[i - 524288]   = qb[i - 524288];
    else if (i < 525056) bqkv[i - 524288]   = kvb[i - 524544];
    else if (i < 525312) bkh[i - 525056]    = f2h(bk[i - 525056]);
  } else if (bid < 6148) {
    int row = (bid - 2052) * 4 + (t >> 6);
    int l = t & 63;
    float4 v = *(const float4*)(feat + (size_t)row * kC + l * 4);
    float s  = v.x + v.y + v.z + v.w;
    float s2 = v.x * v.x + v.y * v.y + v.z * v.z + v.w * v.w;
#pragma unroll
    for (int d = 1; d < 64; d <<= 1) {
      s  += __shfl_xor(s, d, 64);
      s2 += __shfl_xor(s2, d, 64);
    }
    float mu = s * (1.0f / kC);
    float rstd = rsqrtf(s2 * (1.0f / kC) - mu * mu + 1e-5f);
    float4 wv = *(const float4*)(n1w + l * 4);
    float4 bv = *(const float4*)(n1b + l * 4);
    uint2 ov;
    ov.x = ((unsigned int)f2bf((v.y - mu) * rstd * wv.y + bv.y) << 16) |
           f2bf((v.x - mu) * rstd * wv.x + bv.x);
    ov.y = ((unsigned int)f2bf((v.w - mu) * rstd * wv.w + bv.w) << 16) |
           f2bf((v.z - mu) * rstd * wv.z + bv.z);
    *(uint2*)(xln + (size_t)row * kC + l * 4) = ov;
  } else {
    int i = (bid - 6148) * 256 + t;
    int row = i >> 8, m = (i >> 3) & 31, h = i & 7;
    int idx = pe_idx[(size_t)row * 32 + m];
    float acc = pe_b[h];
#pragma unroll
    for (int f = 0; f < 5; ++f)
      acc += pre_table[idx * 5 + f] * pe_w[h * 5 + f];
    acc += (1.0f - cmask[(size_t)row * 32 + m]) * -100.0f;
    posm[(size_t)row * 256 + h * 32 + m] = f2h(acc);
  }
}

// ---- bf16 MFMA GEMM (QKV only): BM=64, BN=256, 8 waves, BK=64 dbuf ---------
template <int EPI, int KDIM>
__global__ __launch_bounds__(512) void gemm64(
    const unsigned short* __restrict__ A, const unsigned short* __restrict__ Wt,
    const float* __restrict__ bias, void* __restrict__ o1,
    unsigned short* __restrict__ o2, unsigned short* __restrict__ o3) {
  __shared__ alignas(16) unsigned short smem[40960];
  unsigned short* As0 = smem;
  unsigned short* Bs0 = smem + 8192;
  int t = threadIdx.x;
  int w = t >> 6, l = t & 63;
  int bm = blockIdx.x * 64, bn = blockIdx.y * 256;

  f32x4 acc[4][2] = {};

  const size_t aoff = (size_t)(bm + w * 8 + (l >> 3)) * KDIM + (l & 7) * 8;
  const size_t boff = (size_t)(bn + w * 32 + (l >> 3)) * KDIM + (l & 7) * 8;
  const int lr = l & 15, lk = l >> 4;

#define STAGE_T(buf, k0)                                                      \
  do {                                                                        \
    GLOAD16(A + aoff + (k0), As0 + (buf)*4096 + w * 512 + l * 8);             \
    GLOAD16(Wt + boff + (k0), Bs0 + (buf)*16384 + w * 2048 + l * 8);          \
    GLOAD16(Wt + boff + (k0) + (size_t)8 * KDIM,                              \
            Bs0 + (buf)*16384 + w * 2048 + 512 + l * 8);                      \
    GLOAD16(Wt + boff + (k0) + (size_t)16 * KDIM,                             \
            Bs0 + (buf)*16384 + w * 2048 + 1024 + l * 8);                     \
    GLOAD16(Wt + boff + (k0) + (size_t)24 * KDIM,                             \
            Bs0 + (buf)*16384 + w * 2048 + 1536 + l * 8);                     \
  } while (0)

  auto compute = [&](int buf) {
#pragma unroll
    for (int kk = 0; kk < 2; ++kk) {
      bf16x8 af[4], bfr[2];
#pragma unroll
      for (int mi = 0; mi < 4; ++mi)
        af[mi] = *(const bf16x8*)(As0 + buf * 4096 + (mi * 16 + lr) * 64 +
                                  kk * 32 + lk * 8);
#pragma unroll
      for (int ni = 0; ni < 2; ++ni)
        bfr[ni] = *(const bf16x8*)(Bs0 + buf * 16384 +
                                   (w * 32 + ni * 16 + lr) * 64 + kk * 32 +
                                   lk * 8);
#pragma unroll
      for (int mi = 0; mi < 4; ++mi)
#pragma unroll
        for (int ni = 0; ni < 2; ++ni)
          acc[mi][ni] = __builtin_amdgcn_mfma_f32_16x16x32_bf16(
              af[mi], bfr[ni], acc[mi][ni], 0, 0, 0);
    }
  };

  STAGE_T(0, 0);
  __syncthreads();
  int cur = 0;
#pragma unroll
  for (int k0 = 64; k0 < KDIM; k0 += 64) {
    STAGE_T(cur ^ 1, k0);
    compute(cur);
    __syncthreads();
    cur ^= 1;
  }
  compute(cur);

#pragma unroll
  for (int mi = 0; mi < 4; ++mi) {
#pragma unroll
    for (int ni = 0; ni < 2; ++ni) {
      int col = bn + w * 32 + ni * 16 + lr;
      float bv = bias[col];
#pragma unroll
      for (int j = 0; j < 4; ++j) {
        int rg = bm + mi * 16 + lk * 4 + j;
        float x = acc[mi][ni][j] + bv;
        if (col < 256) {
          ((unsigned short*)o1)[(size_t)rg * 256 + col] = f2h(x * kScale);
        } else {
          int c = col - 256;
          int h = c >> 6, sbit = (c >> 5) & 1, ch = c & 31;
          unsigned short* dst = sbit ? o3 : o2;
          dst[(size_t)rg * 256 + h * 32 + ch] = f2h(x);
        }
      }
    }
  }
#undef STAGE_T
}

// ---- fused proj+residual+LN2+fc1+gelu+fc2+residual, 64 rows per block ------
__global__ __launch_bounds__(512) void mlp_fused(
    const unsigned short* __restrict__ A,    // attn_out bf16 [16384][256]
    const unsigned short* __restrict__ Wp,   // wproj bf16 [256][256]
    const float* __restrict__ pbias,         // proj_b
    const float* __restrict__ feat,          // residual f32
    const float* __restrict__ w2, const float* __restrict__ b2,
    const unsigned short* __restrict__ W1, const float* __restrict__ b1,
    const unsigned short* __restrict__ W2, const float* __restrict__ b2f,
    float* __restrict__ outp) {
  __shared__ alignas(16) unsigned short sm[66560];
  int t = threadIdx.x;
  int w = t >> 6, l = t & 63;
  int bm = blockIdx.x * 64;
  const int lr = l & 15, lk = l >> 4;

  // ---------------- proj ----------------
  f32x4 accp[4][2] = {};
  {
    const size_t aoff = (size_t)(bm + w * 8 + (l >> 3)) * 256 + (l & 7) * 8;
    const size_t boff = (size_t)(w * 32 + (l >> 3)) * 256 + (l & 7) * 8;
#define PSTAGE(buf, k0)                                                       \
  do {                                                                        \
    GLOAD16(A + aoff + (k0), sm + (buf)*4096 + w * 512 + l * 8);              \
    GLOAD16(Wp + boff + (k0), sm + 8192 + (buf)*16384 + w * 2048 + l * 8);    \
    GLOAD16(Wp + boff + (k0) + (size_t)2048,                                  \
            sm + 8192 + (buf)*16384 + w * 2048 + 512 + l * 8);                \
    GLOAD16(Wp + boff + (k0) + (size_t)4096,                                  \
            sm + 8192 + (buf)*16384 + w * 2048 + 1024 + l * 8);               \
    GLOAD16(Wp + boff + (k0) + (size_t)6144,                                  \
            sm + 8192 + (buf)*16384 + w * 2048 + 1536 + l * 8);               \
  } while (0)
    auto computeP = [&](int buf) {
#pragma unroll
      for (int kk = 0; kk < 2; ++kk) {
        bf16x8 af[4], bfr[2];
#pragma unroll
        for (int mi = 0; mi < 4; ++mi)
          af[mi] = *(const bf16x8*)(sm + buf * 4096 + (mi * 16 + lr) * 64 +
                                    kk * 32 + lk * 8);
#pragma unroll
        for (int ni = 0; ni < 2; ++ni)
          bfr[ni] = *(const bf16x8*)(sm + 8192 + buf * 16384 +
                                     (w * 32 + ni * 16 + lr) * 64 + kk * 32 +
                                     lk * 8);
#pragma unroll
        for (int mi = 0; mi < 4; ++mi)
#pragma unroll
          for (int ni = 0; ni < 2; ++ni)
            accp[mi][ni] = __builtin_amdgcn_mfma_f32_16x16x32_bf16(
                af[mi], bfr[ni], accp[mi][ni], 0, 0, 0);
      }
    };
    PSTAGE(0, 0);
    __syncthreads();
    int cur = 0;
#pragma unroll
    for (int k0 = 64; k0 < 256; k0 += 64) {
      PSTAGE(cur ^ 1, k0);
      computeP(cur);
      __syncthreads();
      cur ^= 1;
    }
    computeP(cur);
#undef PSTAGE
  }

  // ---------------- x = proj + bias + feat (regs + LDS) ----------------
  f32x4 xr[4][2];
  float* xs = (float*)sm;
  __syncthreads();
#pragma unroll
  for (int mi = 0; mi < 4; ++mi) {
#pragma unroll
    for (int ni = 0; ni < 2; ++ni) {
      int c = w * 32 + ni * 16 + lr;
      float bv = pbias[c];
#pragma unroll
      for (int j = 0; j < 4; ++j) {
        int rl = mi * 16 + lk * 4 + j;
        float x = accp[mi][ni][j] + bv + feat[(size_t)(bm + rl) * 256 + c];
        xr[mi][ni][j] = x;
        xs[rl * 260 + c] = x;
      }
    }
  }
  __syncthreads();

  // ---------------- LN2 -> yln (LDS bf16 [64][264] @49664) ----------------
  {
    int r = t >> 3, sub = t & 7;
    float4 xv[8];
    float sx = 0.f, sxx = 0.f;
#pragma unroll
    for (int i = 0; i < 8; ++i) {
      xv[i] = *(const float4*)&xs[r * 260 + sub * 4 + i * 32];
      sx  += xv[i].x + xv[i].y + xv[i].z + xv[i].w;
      sxx += xv[i].x * xv[i].x + xv[i].y * xv[i].y + xv[i].z * xv[i].z +
             xv[i].w * xv[i].w;
    }
#pragma unroll
    for (int d = 1; d < 8; d <<= 1) {
      sx  += __shfl_xor(sx, d, 64);
      sxx += __shfl_xor(sxx, d, 64);
    }
    float mu = sx * (1.0f / 256.0f);
    float rstd = rsqrtf(sxx * (1.0f / 256.0f) - mu * mu + 1e-5f);
#pragma unroll
    for (int i = 0; i < 8; ++i) {
      int c = sub * 4 + i * 32;
      float4 wv = *(const float4*)(w2 + c);
      float4 bv = *(const float4*)(b2 + c);
      uint2 ov;
      ov.x = ((unsigned int)f2bf((xv[i].y - mu) * rstd * wv.y + bv.y) << 16) |
             f2bf((xv[i].x - mu) * rstd * wv.x + bv.x);
      ov.y = ((unsigned int)f2bf((xv[i].w - mu) * rstd * wv.w + bv.w) << 16) |
             f2bf((xv[i].z - mu) * rstd * wv.z + bv.z);
      *(uint2*)&sm[49664 + r * 264 + c] = ov;
    }
  }
  __syncthreads();

  // ---------------- fc1 + gelu -> h1 (LDS bf16 [64][520] @0) ----------------
  const int FB = 33280;
#define F1STAGE(buf, k0, c)                                                   \
  do {                                                                        \
    GLOAD16(W1 + (size_t)((c)*256 + w * 32 + (l >> 2)) * 256 + (k0) +         \
                (l & 3) * 8,                                                  \
            sm + FB + (buf)*8192 + w * 1024 + l * 8);                         \
    GLOAD16(W1 + (size_t)((c)*256 + w * 32 + 16 + (l >> 2)) * 256 + (k0) +    \
                (l & 3) * 8,                                                  \
            sm + FB + (buf)*8192 + w * 1024 + 512 + l * 8);                   \
  } while (0)
#pragma unroll
  for (int c = 0; c < 2; ++c) {
    f32x4 accf[4][2] = {};
    auto computeF1 = [&](int buf, int ka) {
      bf16x8 af[4], bfr[2];
#pragma unroll
      for (int mi = 0; mi < 4; ++mi)
        af[mi] =
            *(const bf16x8*)(sm + 49664 + (mi * 16 + lr) * 264 + ka + lk * 8);
#pragma unroll
      for (int ni = 0; ni < 2; ++ni)
        bfr[ni] = *(const bf16x8*)(sm + FB + buf * 8192 +
                                   (w * 32 + ni * 16 + lr) * 32 + lk * 8);
#pragma unroll
      for (int mi = 0; mi < 4; ++mi)
#pragma unroll
        for (int ni = 0; ni < 2; ++ni)
          accf[mi][ni] = __builtin_amdgcn_mfma_f32_16x16x32_bf16(
              af[mi], bfr[ni], accf[mi][ni], 0, 0, 0);
    };
    F1STAGE(0, 0, c);
    __syncthreads();
    int cur = 0;
#pragma unroll
    for (int k0 = 32; k0 < 256; k0 += 32) {
      F1STAGE(cur ^ 1, k0, c);
      computeF1(cur, k0 - 32);
      __syncthreads();
      cur ^= 1;
    }
    computeF1(cur, 224);
    __syncthreads();
#pragma unroll
    for (int mi = 0; mi < 4; ++mi) {
#pragma unroll
      for (int ni = 0; ni < 2; ++ni) {
        int colg = c * 256 + w * 32 + ni * 16 + lr;
        float bv = b1[colg];
#pragma unroll
        for (int j = 0; j < 4; ++j) {
          float x = accf[mi][ni][j] + bv;
          float g = 0.5f * x * (1.0f + erff(x * 0.70710678118654752f));
          sm[(mi * 16 + lk * 4 + j) * 520 + colg] = f2bf(g);
        }
      }
    }
  }
#undef F1STAGE
  __syncthreads();

  // ---------------- fc2 (K=512, BK=64) + residual -> out ----------------
  f32x4 acc2[4][2] = {};
#define F2STAGE(buf, k0)                                                      \
  do {                                                                        \
    GLOAD16(W2 + (size_t)(w * 32 + (l >> 3)) * 512 + (k0) + (l & 7) * 8,      \
            sm + FB + (buf)*16384 + w * 2048 + l * 8);                        \
    GLOAD16(W2 + (size_t)(w * 32 + 8 + (l >> 3)) * 512 + (k0) + (l & 7) * 8,  \
            sm + FB + (buf)*16384 + w * 2048 + 512 + l * 8);                  \
    GLOAD16(W2 + (size_t)(w * 32 + 16 + (l >> 3)) * 512 + (k0) + (l & 7) * 8, \
            sm + FB + (buf)*16384 + w * 2048 + 1024 + l * 8);                 \
    GLOAD16(W2 + (size_t)(w * 32 + 24 + (l >> 3)) * 512 + (k0) + (l & 7) * 8, \
            sm + FB + (buf)*16384 + w * 2048 + 1536 + l * 8);                 \
  } while (0)
  {
    auto computeF2 = [&](int buf, int ka) {
#pragma unroll
      for (int kk = 0; kk < 2; ++kk) {
        bf16x8 af[4], bfr[2];
#pragma unroll
        for (int mi = 0; mi < 4; ++mi)
          af[mi] = *(const bf16x8*)(sm + (mi * 16 + lr) * 520 + ka + kk * 32 +
                                    lk * 8);
#pragma unroll
        for (int ni = 0; ni < 2; ++ni)
          bfr[ni] = *(const bf16x8*)(sm + FB + buf * 16384 +
                                     (w * 32 + ni * 16 + lr) * 64 + kk * 32 +
                                     lk * 8);
#pragma unroll
        for (int mi = 0; mi < 4; ++mi)
#pragma unroll
          for (int ni = 0; ni < 2; ++ni)
            acc2[mi][ni] = __builtin_amdgcn_mfma_f32_16x16x32_bf16(
                af[mi], bfr[ni], acc2[mi][ni], 0, 0, 0);
      }
    };
    F2STAGE(0, 0);
    __syncthreads();
    int cur = 0;
#pragma unroll
    for (int k0 = 64; k0 < 512; k0 += 64) {
      F2STAGE(cur ^ 1, k0);
      computeF2(cur, k0 - 64);
      __syncthreads();
      cur ^= 1;
    }
    computeF2(cur, 448);
  }
#undef F2STAGE

#pragma unroll
  for (int mi = 0; mi < 4; ++mi) {
#pragma unroll
    for (int ni = 0; ni < 2; ++ni) {
      int col = w * 32 + ni * 16 + lr;
      float bv = b2f[col];
#pragma unroll
      for (int j = 0; j < 4; ++j) {
        int rg = bm + mi * 16 + lk * 4 + j;
        outp[(size_t)rg * 256 + col] = xr[mi][ni][j] + acc2[mi][ni][j] + bv;
      }
    }
  }
}

// -------- Attention: XCD-partitioned, f16, barrier-free waves, dot2 QK ------
__global__ __launch_bounds__(256) void attn_kernel(
    const unsigned short* __restrict__ q, const unsigned short* __restrict__ k,
    const unsigned short* __restrict__ v, const int* __restrict__ member_idx,
    const unsigned short* __restrict__ posm,
    const unsigned short* __restrict__ bkh, const float* __restrict__ blank_v,
    unsigned short* __restrict__ outp) {
  int t = threadIdx.x;
  int w = t >> 6, l = t & 63;
  int bid = blockIdx.x;
  int part = bid & 7;
  int bb = part >> 2, hg = part & 3;
  int row = bb * kN + (bid >> 3) * 4 + w;
  const unsigned int kvbyte = (unsigned int)bb * (kN * 512u);

  __shared__ float        aw[4][2][36];
  __shared__ unsigned int offs[4][32];
  __shared__ float        posl[4][2][32];

  {
    int m = l & 31, hloc = l >> 5;
    posl[w][hloc][m] = h2f(posm[(size_t)row * 256 + hg * 64 + l]);
    if (l < 32)
      offs[w][l] =
          kvbyte + (unsigned int)member_idx[(size_t)row * 32 + l] * 512u;
  }
  WAVE_SYNC();

  const int m8 = l >> 3, ch = l & 7;
  const int hsel = ch >> 2;

  h8 qv8 = *(const h8*)(q + (size_t)row * 256 + hg * 64 + ch * 8);
  const h2* qa = (const h2*)&qv8;

  float lg[4];
#pragma unroll
  for (int i = 0; i < 4; ++i) {
    int mi = i * 8 + m8;
    const char* kp = (const char*)k + offs[w][mi] + hg * 128 + ch * 16;
    h8 kv = *(const h8*)kp;
    const h2* ka = (const h2*)&kv;
    float p = 0.f;
#pragma unroll
    for (int e = 0; e < 4; ++e) p = fdot2f(qa[e], ka[e], p);
    p += __shfl_xor(p, 1, 64);
    p += __shfl_xor(p, 2, 64);
    lg[i] = p + posl[w][hsel][mi];
  }

  float bl = 0.f;
  {
    h8 bk8 = *(const h8*)(bkh + hg * 64 + ch * 8);
    const h2* ba = (const h2*)&bk8;
#pragma unroll
    for (int e = 0; e < 4; ++e) bl = fdot2f(qa[e], ba[e], bl);
    bl += __shfl_xor(bl, 1, 64);
    bl += __shfl_xor(bl, 2, 64);
    bl = fminf(fmaxf(bl, -5.0f), 5.0f);
  }

  float mx = fmaxf(fmaxf(lg[0], lg[1]), fmaxf(lg[2], lg[3]));
  mx = fmaxf(mx, __shfl_xor(mx, 8, 64));
  mx = fmaxf(mx, __shfl_xor(mx, 16, 64));
  mx = fmaxf(mx, __shfl_xor(mx, 32, 64));
  mx = fmaxf(mx, bl);
  float e4[4], s = 0.f;
#pragma unroll
  for (int i = 0; i < 4; ++i) { e4[i] = __expf(lg[i] - mx); s += e4[i]; }
  s += __shfl_xor(s, 8, 64);
  s += __shfl_xor(s, 16, 64);
  s += __shfl_xor(s, 32, 64);
  float eb = __expf(bl - mx);
  s += eb;
  float inv = __builtin_amdgcn_rcpf(s);
  if ((ch & 3) == 0) {
#pragma unroll
    for (int i = 0; i < 4; ++i) aw[w][hsel][i * 8 + m8] = e4[i] * inv;
    if (m8 == 0) aw[w][hsel][32] = eb * inv;
  }
  WAVE_SYNC();

  const int hp = l >> 5, sq = (l >> 3) & 3, c8 = l & 7;
  const char* vb = (const char*)v + (hg * 2 + hp) * 64 + c8 * 8;
  float a0 = 0.f, a1 = 0.f, a2 = 0.f, a3 = 0.f;
#pragma unroll
  for (int i = 0; i < 8; ++i) {
    int mm = sq * 8 + i;
    float a = aw[w][hp][mm];
    h4 u = *(const h4*)(vb + offs[w][mm]);
    a0 = fmaf(a, (float)u[0], a0);
    a1 = fmaf(a, (float)u[1], a1);
    a2 = fmaf(a, (float)u[2], a2);
    a3 = fmaf(a, (float)u[3], a3);
  }
  a0 += __shfl_xor(a0, 8, 64);  a1 += __shfl_xor(a1, 8, 64);
  a2 += __shfl_xor(a2, 8, 64);  a3 += __shfl_xor(a3, 8, 64);
  a0 += __shfl_xor(a0, 16, 64); a1 += __shfl_xor(a1, 16, 64);
  a2 += __shfl_xor(a2, 16, 64); a3 += __shfl_xor(a3, 16, 64);
  if (sq == 0) {
    float ab = aw[w][hp][32];
    int c = (hg * 2 + hp) * 32 + c8 * 4;
    float4 bv = *(const float4*)(blank_v + c);
    a0 = fmaf(ab, bv.x, a0);
    a1 = fmaf(ab, bv.y, a1);
    a2 = fmaf(ab, bv.z, a2);
    a3 = fmaf(ab, bv.w, a3);
    uint2 o;
    o.x = ((unsigned int)f2bf(a1) << 16) | f2bf(a0);
    o.y = ((unsigned int)f2bf(a3) << 16) | f2bf(a2);
    *(uint2*)(outp + (size_t)row * 256 + c) = o;
  }
}

extern "C" void kernel_launch(void* const* d_in, const int* in_sizes, int n_in,
                              void* d_out, int out_size, void* d_ws, size_t ws_size,
                              hipStream_t stream) {
  const float* feat       = (const float*)d_in[0];
  const int*   member_idx = (const int*)d_in[1];
  const float* cmask      = (const float*)d_in[2];
  const int*   pe_idx     = (const int*)d_in[3];
  const float* pre_table  = (const float*)d_in[5];
  const float* n1w        = (const float*)d_in[6];
  const float* n1b        = (const float*)d_in[7];
  const float* q_w        = (const float*)d_in[8];
  const float* q_b        = (const float*)d_in[9];
  const float* kv_w       = (const float*)d_in[10];
  const float* kv_b       = (const float*)d_in[11];
  const float* blank_k    = (const float*)d_in[12];
  const float* blank_v    = (const float*)d_in[13];
  const float* pe_w       = (const float*)d_in[14];
  const float* pe_b       = (const float*)d_in[15];
  const float* proj_w     = (const float*)d_in[16];
  const float* proj_b     = (const float*)d_in[17];
  const float* n2w        = (const float*)d_in[18];
  const float* n2b        = (const float*)d_in[19];
  const float* fc1_w      = (const float*)d_in[20];
  const float* fc1_b      = (const float*)d_in[21];
  const float* fc2_w      = (const float*)d_in[22];
  const float* fc2_b      = (const float*)d_in[23];

  float* out = (float*)d_out;
  unsigned char* ws = (unsigned char*)d_ws;

  unsigned short* xln   = (unsigned short*)(ws + 0);           // 8 MB, later attn_out
  unsigned short* q_buf = (unsigned short*)(ws + 8388608);     // 8 MB f16
  unsigned short* k_buf = (unsigned short*)(ws + 16777216);    // 8 MB f16
  unsigned short* v_buf = (unsigned short*)(ws + 25165824);    // 8 MB f16
  unsigned short* wqkv  = (unsigned short*)(ws + 33554432);    // 384 KB
  unsigned short* wproj = (unsigned short*)(ws + 33947648);    // 128 KB
  unsigned short* wfc1  = (unsigned short*)(ws + 34078720);    // 256 KB
  unsigned short* wfc2  = (unsigned short*)(ws + 34340864);    // 256 KB
  float*          bqkv  = (float*)(ws + 34603008);             // 3 KB
  unsigned short* bkh   = (unsigned short*)(ws + 34606080);    // 512 B
  unsigned short* attn_out = xln;
  unsigned short* posm  = (unsigned short*)out;  // d_out dead until mlp_fused

  prep_kernel<<<22532, 256, 0, stream>>>(
      q_w, kv_w, proj_w, fc1_w, fc2_w, q_b, kv_b, blank_k, feat, n1w, n1b,
      pe_idx, pre_table, pe_w, pe_b, cmask, wqkv, wproj, wfc1, wfc2, bqkv,
      bkh, xln, posm);

  gemm64<0, 256><<<dim3(kRowsTotal / 64, 3), 512, 0, stream>>>(
      xln, wqkv, bqkv, q_buf, k_buf, v_buf);

  attn_kernel<<<kRowsTotal, 256, 0, stream>>>(
      q_buf, k_buf, v_buf, member_idx, posm, bkh, blank_v, attn_out);

  mlp_fused<<<kRowsTotal / 64, 512, 0, stream>>>(
      attn_out, wproj, proj_b, feat, n2w, n2b, wfc1, fc1_b, wfc2, fc2_b, out);
}